// Round 6
// baseline (3980.795 us; speedup 1.0000x reference)
//
#include <hip/hip_runtime.h>

typedef unsigned int u32;
typedef unsigned short u16;
typedef __attribute__((ext_vector_type(4))) float f32x4;
typedef __attribute__((ext_vector_type(8))) short bf16x8;

#define DEV static __device__ __forceinline__

DEV float sigf(float x){ return 1.0f/(1.0f + expf(-x)); }

DEV u16 f2bf(float x){
  u32 u = __float_as_uint(x);
  u32 r = (u + 0x7FFFu + ((u >> 16) & 1u)) >> 16;
  return (u16)r;
}

DEV u32 encf(float f){
  u32 u = __float_as_uint(f);
  return (u & 0x80000000u) ? ~u : (u | 0x80000000u);
}
DEV float decf(u32 e){
  return (e & 0x80000000u) ? __uint_as_float(e ^ 0x80000000u) : __uint_as_float(~e);
}

DEV void gload16(const void* g, void* l){
  __builtin_amdgcn_global_load_lds((const __attribute__((address_space(1))) u32*)g,
                                   (__attribute__((address_space(3))) u32*)l, 16, 0, 0);
}

// ---------------------------------------------------------------------------
// bf16 MFMA GEMM: C[n][m] = sum_k A[m][k]*B[n][k] + bias[m]  (f32 out)
// Tiles 128x128, BK=32. Dual weights via grid.z. (input-gate GEMMs)
// ---------------------------------------------------------------------------
__global__ __launch_bounds__(256,2) void gemm_bf16(
    const u16* __restrict__ A, const u16* __restrict__ A2,
    const u16* __restrict__ B,
    const float* __restrict__ bias, const float* __restrict__ bias2,
    float* __restrict__ C, float* __restrict__ C2, int ldc,
    int Kp, int ksteps)
{
  __shared__ u16 lds[(128 + 128)*32];
  char* ldsc = (char*)&lds[0];
  const int Boff = 128*64;
  const int tid = threadIdx.x;
  const int l = tid & 63, w = tid >> 6;
  const int n0 = blockIdx.x * 128, m0 = blockIdx.y * 128;
  const u16* Ause = blockIdx.z ? A2 : A;
  const float* buse = blockIdx.z ? bias2 : bias;
  float* Cuse = blockIdx.z ? C2 : C;
  const int wr = w >> 1, wc = w & 1;
  const int lr = l & 15, g = l >> 4;

  f32x4 acc[4][4];
  #pragma unroll
  for (int i=0;i<4;++i)
    #pragma unroll
    for (int j=0;j<4;++j) acc[i][j] = f32x4{0.f,0.f,0.f,0.f};

  for (int ks = 0; ks < ksteps; ++ks) {
    const int i0 = ks*32;
    __syncthreads();
    #pragma unroll
    for (int r = 0; r < 2; ++r) {
      const int rr = w*2 + r;
      const int c = rr*64 + l;
      const int row = c >> 2, bpos = c & 3;
      const int ib = bpos ^ ((row>>1) & 3);
      gload16(Ause + ((size_t)(m0 + row)*Kp + (i0 + ib*8)), ldsc + rr*1024);
      gload16(B    + ((size_t)(n0 + row)*Kp + (i0 + ib*8)), ldsc + Boff + rr*1024);
    }
    __syncthreads();
    bf16x8 af[4], bfr[4];
    #pragma unroll
    for (int m=0;m<4;++m){
      int o = wr*64 + m*16 + lr;
      af[m] = *(const bf16x8*)(ldsc + o*64 + ((g ^ ((o>>1)&3))<<4));
    }
    #pragma unroll
    for (int n=0;n<4;++n){
      int pr = wc*64 + n*16 + lr;
      bfr[n] = *(const bf16x8*)(ldsc + Boff + pr*64 + ((g ^ ((pr>>1)&3))<<4));
    }
    #pragma unroll
    for (int m=0;m<4;++m)
      #pragma unroll
      for (int n=0;n<4;++n)
        acc[m][n] = __builtin_amdgcn_mfma_f32_16x16x32_bf16(af[m], bfr[n], acc[m][n], 0,0,0);
  }

  #pragma unroll
  for (int m=0;m<4;++m){
    int mm = m0 + wr*64 + m*16 + g*4;
    f32x4 bv = *(const f32x4*)(buse + mm);
    #pragma unroll
    for (int n=0;n<4;++n){
      int p = n0 + wc*64 + n*16 + lr;
      f32x4 v;
      #pragma unroll
      for (int r2=0;r2<4;++r2) v[r2] = acc[m][n][r2] + bv[r2];
      *(f32x4*)(Cuse + (size_t)p*ldc + mm) = v;
    }
  }
}

// ---------------------------------------------------------------------------
// bf16 MFMA GEMM, split-K, atomicAdd into pre-initialized f32 C.
// ---------------------------------------------------------------------------
__global__ __launch_bounds__(256,2) void gemm_bf16_sk(
    const u16* __restrict__ A, const u16* __restrict__ B,
    float* __restrict__ C, int ldc, int Kp, int kpc)
{
  __shared__ u16 lds[(128 + 128)*32];
  char* ldsc = (char*)&lds[0];
  const int Boff = 128*64;
  const int tid = threadIdx.x;
  const int l = tid & 63, w = tid >> 6;
  const int n0 = blockIdx.x * 128, m0 = blockIdx.y * 128;
  const int ks0 = blockIdx.z * kpc;
  const int wr = w >> 1, wc = w & 1;
  const int lr = l & 15, g = l >> 4;

  f32x4 acc[4][4];
  #pragma unroll
  for (int i=0;i<4;++i)
    #pragma unroll
    for (int j=0;j<4;++j) acc[i][j] = f32x4{0.f,0.f,0.f,0.f};

  for (int ks = 0; ks < kpc; ++ks) {
    const int i0 = (ks0 + ks)*32;
    __syncthreads();
    #pragma unroll
    for (int r = 0; r < 2; ++r) {
      const int rr = w*2 + r;
      const int c = rr*64 + l;
      const int row = c >> 2, bpos = c & 3;
      const int ib = bpos ^ ((row>>1) & 3);
      gload16(A + ((size_t)(m0 + row)*Kp + (i0 + ib*8)), ldsc + rr*1024);
      gload16(B + ((size_t)(n0 + row)*Kp + (i0 + ib*8)), ldsc + Boff + rr*1024);
    }
    __syncthreads();
    bf16x8 af[4], bfr[4];
    #pragma unroll
    for (int m=0;m<4;++m){
      int o = wr*64 + m*16 + lr;
      af[m] = *(const bf16x8*)(ldsc + o*64 + ((g ^ ((o>>1)&3))<<4));
    }
    #pragma unroll
    for (int n=0;n<4;++n){
      int pr = wc*64 + n*16 + lr;
      bfr[n] = *(const bf16x8*)(ldsc + Boff + pr*64 + ((g ^ ((pr>>1)&3))<<4));
    }
    #pragma unroll
    for (int m=0;m<4;++m)
      #pragma unroll
      for (int n=0;n<4;++n)
        acc[m][n] = __builtin_amdgcn_mfma_f32_16x16x32_bf16(af[m], bfr[n], acc[m][n], 0,0,0);
  }

  #pragma unroll
  for (int m=0;m<4;++m){
    int mm = m0 + wr*64 + m*16 + g*4;
    #pragma unroll
    for (int n=0;n<4;++n){
      int p = n0 + wc*64 + n*16 + lr;
      float* dst = C + (size_t)p*ldc + mm;
      #pragma unroll
      for (int r2=0;r2<4;++r2) atomicAdd(dst + r2, acc[m][n][r2]);
    }
  }
}

// C[i] = bias ? bias[i & mmask] : 0
__global__ void initc(float* __restrict__ C, const float* __restrict__ bias,
                      int total, int mmask)
{
  int i = blockIdx.x*256 + threadIdx.x;
  if (i < total) C[i] = bias ? bias[i & mmask] : 0.f;
}

// ---------------------------------------------------------------------------
// Fused GRU step (f32): gh = h_prev @ W_hh^T + b_hh, gates, h update.
// Grid (32 jg, 4 bg, 2 dir), 256 thr.
// ---------------------------------------------------------------------------
__global__ __launch_bounds__(256) void gru_step(
    const float* __restrict__ xg0, const float* __restrict__ xg1,
    const float* __restrict__ whh0, const float* __restrict__ whh1,
    const float* __restrict__ bhh0, const float* __restrict__ bhh1,
    float* __restrict__ hs, int S, int t)
{
  __shared__ float hL[32*520];
  __shared__ float wL[48*132];
  const int tid = threadIdx.x;
  const int tj = tid & 15, tb = tid >> 4;
  const int jg = blockIdx.x;
  const int b0 = blockIdx.y*32;
  const int dir = blockIdx.z;
  const int l = tid & 63, w = tid >> 6;
  const float* xg  = dir ? xg1  : xg0;
  const float* whh = dir ? whh1 : whh0;
  const float* bhh = dir ? bhh1 : bhh0;
  const int tt = dir ? (S-1-t) : t;
  const int j = jg*16 + tj;

  float accr[2], accz[2], accn[2];
  {
    float br = bhh[j], bz = bhh[512+j], bn = bhh[1024+j];
    accr[0]=br; accr[1]=br; accz[0]=bz; accz[1]=bz; accn[0]=bn; accn[1]=bn;
  }

  if (t > 0){
    const int tp = dir ? (tt+1) : (tt-1);
    #pragma unroll
    for (int rr = 0; rr < 8; ++rr){
      int row = w*8 + rr;
      const float* srcb = hs + ((size_t)(b0+row)*S + tp)*1024 + dir*512;
      gload16(srcb + l*4,       (char*)hL + (size_t)(row*520)*4);
      gload16(srcb + 256 + l*4, (char*)hL + (size_t)(row*520 + 256)*4);
    }
    for (int c = 0; c < 4; ++c){
      const int k0 = c*128;
      __syncthreads();
      #pragma unroll
      for (int i = 0; i < 6; ++i){
        int qidx = tid + i*256;
        int row = qidx >> 5, q = qidx & 31;
        int grow = (row>>4)*512 + jg*16 + (row & 15);
        f32x4 v = *(const f32x4*)(whh + (size_t)grow*512 + k0 + q*4);
        *(f32x4*)(wL + row*132 + q*4) = v;
      }
      __syncthreads();
      #pragma unroll 4
      for (int q = 0; q < 32; ++q){
        f32x4 ha  = *(const f32x4*)(hL + (2*tb  )*520 + k0 + q*4);
        f32x4 hb  = *(const f32x4*)(hL + (2*tb+1)*520 + k0 + q*4);
        f32x4 wr4 = *(const f32x4*)(wL + tj*132      + q*4);
        f32x4 wz4 = *(const f32x4*)(wL + (16+tj)*132 + q*4);
        f32x4 wn4 = *(const f32x4*)(wL + (32+tj)*132 + q*4);
        #pragma unroll
        for (int e = 0; e < 4; ++e){
          accr[0] += ha[e]*wr4[e]; accz[0] += ha[e]*wz4[e]; accn[0] += ha[e]*wn4[e];
          accr[1] += hb[e]*wr4[e]; accz[1] += hb[e]*wz4[e]; accn[1] += hb[e]*wn4[e];
        }
      }
    }
  }

  #pragma unroll
  for (int bi = 0; bi < 2; ++bi){
    int lb = 2*tb + bi;
    int b = b0 + lb;
    size_t xbase = ((size_t)b*S + tt)*1536;
    float gir = xg[xbase + j], giz = xg[xbase + 512 + j], gin = xg[xbase + 1024 + j];
    float hp = (t>0) ? hL[lb*520 + j] : 0.f;
    float r = sigf(gir + accr[bi]);
    float z = sigf(giz + accz[bi]);
    float n = tanhf(gin + r*accn[bi]);
    hs[((size_t)b*S + tt)*1024 + dir*512 + j] = (1.f - z)*n + z*hp;
  }
}

// sent [b][80][1024] f32 -> sentT [b][1024][96] bf16 (s in [80,96) zero pad)
__global__ void transpose_sent(const float* __restrict__ sent, u16* __restrict__ sentT)
{
  __shared__ float tl[80][65];
  int b = blockIdx.y, h0 = blockIdx.x*64;
  for (int idx = threadIdx.x; idx < 80*64; idx += 256){
    int s = idx >> 6, hh = idx & 63;
    tl[s][hh] = sent[((size_t)b*80 + s)*1024 + h0 + hh];
  }
  __syncthreads();
  for (int idx = threadIdx.x; idx < 64*96; idx += 256){
    int hh = idx / 96, s = idx % 96;
    sentT[((size_t)b*1024 + h0 + hh)*96 + s] = (s < 80) ? f2bf(tl[s][hh]) : (u16)0;
  }
}

__global__ void attn_scores(const float* __restrict__ sent, const float* __restrict__ u,
                            const float* __restrict__ attn_b, float* __restrict__ sc)
{
  int wid = blockIdx.x*4 + (threadIdx.x >> 6);
  int lane = threadIdx.x & 63;
  const float* row = sent + (size_t)wid*1024;
  const float* ub = u + (size_t)(wid/80)*1024;
  float acc = 0.f;
  for (int h = lane; h < 1024; h += 64) acc += row[h]*(ub[h] + attn_b[h]);
  #pragma unroll
  for (int m = 32; m; m >>= 1) acc += __shfl_xor(acc, m);
  if (lane == 0) sc[wid] = acc;
}

// one wave per batch row; 80 values over 64 lanes (lanes 0-15 carry 2)
__global__ void softmax80(const float* __restrict__ sc, float* __restrict__ a)
{
  int b = blockIdx.x, l = threadIdx.x;
  float v0 = sc[b*80 + l];
  float v1 = (l < 16) ? sc[b*80 + 64 + l] : -1e30f;
  float mx = fmaxf(v0, v1);
  #pragma unroll
  for (int m = 32; m; m >>= 1) mx = fmaxf(mx, __shfl_xor(mx, m));
  float e0 = expf(v0 - mx);
  float e1 = (l < 16) ? expf(v1 - mx) : 0.f;
  float s = e0 + e1;
  #pragma unroll
  for (int m = 32; m; m >>= 1) s += __shfl_xor(s, m);
  float inv = 1.f/s;
  a[b*80 + l] = e0*inv;
  if (l < 16) a[b*80 + 64 + l] = e1*inv;
}

__global__ void par_cs0(const float* __restrict__ a, const float* __restrict__ sent,
                        const float* __restrict__ cv, float* __restrict__ Cs0)
{
  int b = blockIdx.x;
  for (int h = threadIdx.x; h < 1024; h += 256){
    float acc = 0.f;
    for (int s = 0; s < 80; ++s) acc += a[b*80+s]*sent[((size_t)b*80+s)*1024 + h];
    Cs0[(size_t)b*2048 + 1024 + h] = acc;
    Cs0[(size_t)b*2048 + h] = cv[(size_t)b*1024 + h];
  }
}

// pack conv weight [O][CIs][3] f32 -> [3][O][CIp] bf16
__global__ void pack_w(const float* __restrict__ src, u16* __restrict__ dst,
                       int O, int CIs, int CIp)
{
  int i = blockIdx.x*256 + threadIdx.x;
  int total = 3*O*CIp;
  if (i >= total) return;
  int tap = i/(O*CIp); int rem = i%(O*CIp); int o = rem/CIp, ci = rem%CIp;
  float v = (ci < CIs) ? src[((size_t)o*CIs + ci)*3 + tap] : 0.f;
  dst[((size_t)tap*O + o)*CIp + ci] = f2bf(v);
}

// pack dense weight [M][Ks] f32 -> [M][Kp] bf16 (zero pad)
__global__ void pack_wk(const float* __restrict__ src, u16* __restrict__ dst,
                        int M, int Ks, int Kp)
{
  int i = blockIdx.x*256 + threadIdx.x;
  if (i >= M*Kp) return;
  int row = i/Kp, k = i%Kp;
  dst[i] = (k < Ks) ? f2bf(src[(size_t)row*Ks + k]) : (u16)0;
}

// elementwise f32 -> bf16
__global__ void pack_f2b(const float* __restrict__ src, u16* __restrict__ dst, int n)
{
  int i = blockIdx.x*256 + threadIdx.x;
  if (i < n) dst[i] = f2bf(src[i]);
}

// gather+pack embeddings: rows R, dst [R][320] bf16
__global__ void pack_x(const float* __restrict__ emb, const int* __restrict__ toks,
                       int rdiv, int rmul, u16* __restrict__ dst, int R)
{
  int i = blockIdx.x*256 + threadIdx.x;
  if (i >= R*320) return;
  int row = i/320, k = i%320;
  int tok = toks[(row/rdiv)*rmul + (row%rdiv)];
  dst[i] = (k < 300) ? f2bf(emb[(size_t)tok*300 + k]) : (u16)0;
}

__global__ void prep_ab(const float* c11b, const float* c13b, const float* c21b, const float* c23b,
                        const float* g1, const float* b1, const float* m1, const float* v1,
                        const float* g2, const float* b2, const float* m2, const float* v2,
                        float* ab)
{
  int i = blockIdx.x*256 + threadIdx.x;
  if (i >= 4096) return;
  int layer = i >> 10, o = i & 1023;
  float al, be;
  if (layer == 0){ al = g1[o]/sqrtf(v1[o]+1e-5f); be = c11b[o]*al + b1[o] - m1[o]*al; }
  else if (layer == 1){ al = 1.f; be = c13b[o]; }
  else if (layer == 2){ al = g2[o]/sqrtf(v2[o]+1e-5f); be = c21b[o]*al + b2[o] - m2[o]*al; }
  else { al = 1.f; be = c23b[o]; }
  ab[layer*2048 + o] = al;
  ab[layer*2048 + 1024 + o] = be;
}

__global__ void init_penc(u32* p){
  int i = blockIdx.x*256 + threadIdx.x;
  if (i < 128*1024) p[i] = encf(-3.3e38f);
}
__global__ void dec_p(const u32* __restrict__ pe, float* __restrict__ pf){
  int i = blockIdx.x*256 + threadIdx.x;
  if (i < 128*1024) pf[i] = decf(pe[i]);
}

// ---------------------------------------------------------------------------
// Conv layer as 3-tap MFMA GEMM, dbuf + COUNTED vmcnt (T4) + setprio (T5).
// Tile: 256 o x 256 p, 512 thr = 8 waves (2 wr x 4 wc), wave = 128o x 64p.
// Per-wave stage = EXACTLY 9 global_load_lds (6 A + 3 B; B tail exec-masked
// l<8 so every wave issues it). Loop: stage(next) -> s_waitcnt vmcnt(9)
// (prev tile done, new stage stays in flight) -> s_barrier -> MFMA ->
// lgkmcnt(0) -> s_barrier. No vmcnt(0) drain in steady state.
// ---------------------------------------------------------------------------
#define CONV_STAGE(DST, I0)                                                   \
  {                                                                           \
    _Pragma("unroll")                                                         \
    for (int r = 0; r < 6; ++r) {                                             \
      const int c = r*512 + tid;                                              \
      const int row = c >> 2, bpos = c & 3;                                   \
      const int tap = row >> 8, o = row & 255;                                \
      const int ib = bpos ^ ((row>>1) & 3);                                   \
      gload16(Wt + ((size_t)(tap*1024 + o0 + o)*CI + ((I0) + ib*8)),          \
              (DST) + (size_t)c*16);                                          \
    }                                                                         \
    _Pragma("unroll")                                                         \
    for (int r = 0; r < 2; ++r) {                                             \
      const int c = w*136 + r*64 + l;                                         \
      const int row = c >> 2, bpos = c & 3;                                   \
      const int ib = bpos ^ ((row>>1) & 3);                                   \
      int ps = p0 + row; ps = ps < P_in ? ps : (P_in - 1);                    \
      gload16(Xb + ((size_t)ps*CI + ((I0) + ib*8)),                           \
              (DST) + BOFF + (size_t)c*16);                                   \
    }                                                                         \
    if (l < 8) {                                                              \
      const int c = w*136 + 128 + l;                                          \
      const int row = c >> 2, bpos = c & 3;                                   \
      const int ib = bpos ^ ((row>>1) & 3);                                   \
      int ps = p0 + row; ps = ps < P_in ? ps : (P_in - 1);                    \
      gload16(Xb + ((size_t)ps*CI + ((I0) + ib*8)),                           \
              (DST) + BOFF + (size_t)c*16);                                   \
    }                                                                         \
  }

__global__ __launch_bounds__(512,2) void conv_mfma(
    const u16* __restrict__ X, long bstrideX,
    const u16* __restrict__ Wt,
    const float* __restrict__ alpha, const float* __restrict__ beta,
    u16* __restrict__ Y, long bstrideY,
    u32* __restrict__ Penc, int b0,
    int P_in, int P_out, int CI, int dil, int ksteps, int mode)
{
  __shared__ u16 lds[66560];           // 133120 B total (2 x 66560 B buffers)
  char* ldsc = (char*)&lds[0];
  const int BUF = 66560;
  const int BOFF = 768*64;             // A rows then B rows
  const int tid = threadIdx.x;
  const int l = tid & 63, w = tid >> 6;
  const int wg = blockIdx.x + (blockIdx.y<<2) + (blockIdx.z<<4);
  const int id2 = ((wg & 7) << 5) | (wg >> 3);       // XCD swizzle (bijective)
  const int p0 = (id2 & 3) * 256;
  const int o0 = ((id2 >> 2) & 3) * 256;
  const int bz = id2 >> 4;
  const u16* Xb = X + (size_t)bz * (size_t)bstrideX;
  const int wr = w >> 2, wc = w & 3;
  const int lr = l & 15, g = l >> 4;

  f32x4 acc[8][4];
  #pragma unroll
  for (int i=0;i<8;++i)
    #pragma unroll
    for (int j=0;j<4;++j) acc[i][j] = f32x4{0.f,0.f,0.f,0.f};

  // prologue: stage K-tile 0 into buf0 (9 loads/wave in flight)
  CONV_STAGE(ldsc, 0)

  for (int ks = 0; ks < ksteps; ++ks) {
    const int cur = ks & 1;
    if (ks + 1 < ksteps) {
      char* dst = ldsc + (cur^1)*BUF;
      CONV_STAGE(dst, (ks+1)*32)
      // prev tile's 9 loads done; the 9 just issued stay in flight
      asm volatile("s_waitcnt vmcnt(9)" ::: "memory");
    } else {
      asm volatile("s_waitcnt vmcnt(0)" ::: "memory");
    }
    __builtin_amdgcn_s_barrier();
    asm volatile("" ::: "memory");     // fence: no LDS read hoists above barrier

    char* src = ldsc + cur*BUF;
    __builtin_amdgcn_s_setprio(1);
    #pragma unroll
    for (int tap = 0; tap < 3; ++tap) {
      bf16x8 af[8];
      #pragma unroll
      for (int m=0;m<8;++m){
        int o = wr*128 + m*16 + lr;
        int row = tap*256 + o;
        af[m] = *(const bf16x8*)(src + row*64 + ((g ^ ((row>>1)&3))<<4));
      }
      #pragma unroll
      for (int n=0;n<4;++n){
        int pr = wc*64 + n*16 + lr + dil*tap;
        bf16x8 bfr = *(const bf16x8*)(src + BOFF + pr*64 + ((g ^ ((pr>>1)&3))<<4));
        #pragma unroll
        for (int m=0;m<8;++m)
          acc[m][n] = __builtin_amdgcn_mfma_f32_16x16x32_bf16(af[m], bfr, acc[m][n], 0,0,0);
      }
    }
    __builtin_amdgcn_s_setprio(0);

    asm volatile("s_waitcnt lgkmcnt(0)" ::: "memory");
    __builtin_amdgcn_s_barrier();
    asm volatile("" ::: "memory");     // fence: next stage can't hoist above
  }

  if (mode == 2) {
    #pragma unroll
    for (int m=0;m<8;++m){
      int oo = o0 + wr*128 + m*16 + g*4;
      f32x4 al = *(const f32x4*)(alpha + oo);
      f32x4 be = *(const f32x4*)(beta + oo);
      float vm[4] = {-1e30f,-1e30f,-1e30f,-1e30f};
      #pragma unroll
      for (int n=0;n<4;++n){
        int p = p0 + wc*64 + n*16 + lr;
        bool ok = p < P_out;
        #pragma unroll
        for (int r2=0;r2<4;++r2){
          float v = acc[m][n][r2]*al[r2] + be[r2];
          vm[r2] = ok ? fmaxf(vm[r2], v) : vm[r2];
        }
      }
      #pragma unroll
      for (int r2=0;r2<4;++r2){
        float v = vm[r2];
        #pragma unroll
        for (int mask=1; mask<16; mask<<=1) v = fmaxf(v, __shfl_xor(v, mask));
        if (lr == 0) atomicMax(&Penc[(size_t)(b0+bz)*1024 + oo + r2], encf(v));
      }
    }
  } else {
    #pragma unroll
    for (int m=0;m<8;++m){
      int oo = o0 + wr*128 + m*16 + g*4;
      f32x4 al = *(const f32x4*)(alpha + oo);
      f32x4 be = *(const f32x4*)(beta + oo);
      #pragma unroll
      for (int n=0;n<4;++n){
        int p = p0 + wc*64 + n*16 + lr;
        if (p < P_out){
          float v0 = acc[m][n][0]*al[0] + be[0];
          float v1 = acc[m][n][1]*al[1] + be[1];
          float v2 = acc[m][n][2]*al[2] + be[2];
          float v3 = acc[m][n][3]*al[3] + be[3];
          if (mode == 0){ v0=fmaxf(v0,0.f); v1=fmaxf(v1,0.f); v2=fmaxf(v2,0.f); v3=fmaxf(v3,0.f); }
          uint2 pk;
          pk.x = (u32)f2bf(v0) | ((u32)f2bf(v1) << 16);
          pk.y = (u32)f2bf(v2) | ((u32)f2bf(v3) << 16);
          *(uint2*)(Y + (size_t)bz*(size_t)bstrideY + (size_t)p*1024 + oo) = pk;
        }
      }
    }
  }
}

__global__ void head_final(const float* __restrict__ Cs0, const float* __restrict__ t1,
                           const float* __restrict__ t2, const float* __restrict__ outb,
                           float* __restrict__ dout)
{
  __shared__ float red[256];
  int b = blockIdx.x;
  float part = 0.f;
  for (int gg = threadIdx.x; gg < 2048; gg += 256){
    float cd = Cs0[(size_t)b*2048+gg] * sigf(t1[(size_t)b*2048+gg]);
    part += cd * (t2[(size_t)b*2048+gg] + outb[gg]);
  }
  red[threadIdx.x] = part;
  __syncthreads();
  for (int s = 128; s > 0; s >>= 1){
    if (threadIdx.x < s) red[threadIdx.x] += red[threadIdx.x + s];
    __syncthreads();
  }
  if (threadIdx.x < 4) dout[b*4 + threadIdx.x] = red[0];
}

// ---------------------------------------------------------------------------
extern "C" void kernel_launch(void* const* d_in, const int* in_sizes, int n_in,
                              void* d_out, int out_size, void* d_ws, size_t ws_size,
                              hipStream_t stream)
{
  (void)in_sizes; (void)n_in; (void)out_size; (void)ws_size;
  const int*   input_batch = (const int*)d_in[0];
  const int*   choices     = (const int*)d_in[1];
  const float* emb    = (const float*)d_in[2];
  const float* sgwihf = (const float*)d_in[3];
  const float* sgwhhf = (const float*)d_in[4];
  const float* sgbihf = (const float*)d_in[5];
  const float* sgbhhf = (const float*)d_in[6];
  const float* sgwihb = (const float*)d_in[7];
  const float* sgwhhb = (const float*)d_in[8];
  const float* sgbihb = (const float*)d_in[9];
  const float* sgbhhb = (const float*)d_in[10];
  const float* cgwihf = (const float*)d_in[11];
  const float* cgwhhf = (const float*)d_in[12];
  const float* cgbihf = (const float*)d_in[13];
  const float* cgbhhf = (const float*)d_in[14];
  const float* cgwihb = (const float*)d_in[15];
  const float* cgwhhb = (const float*)d_in[16];
  const float* cgbihb = (const float*)d_in[17];
  const float* cgbhhb = (const float*)d_in[18];
  const float* lin_w  = (const float*)d_in[19];
  const float* lin_b  = (const float*)d_in[20];
  const float* attn_w = (const float*)d_in[21];
  const float* attn_b = (const float*)d_in[22];
  const float* c11w = (const float*)d_in[23];
  const float* c11b = (const float*)d_in[24];
  const float* c13w = (const float*)d_in[25];
  const float* c13b = (const float*)d_in[26];
  const float* c21w = (const float*)d_in[27];
  const float* c21b = (const float*)d_in[28];
  const float* c23w = (const float*)d_in[29];
  const float* c23b = (const float*)d_in[30];
  const float* bn1g = (const float*)d_in[31];
  const float* bn1b = (const float*)d_in[32];
  const float* bn1m = (const float*)d_in[33];
  const float* bn1v = (const float*)d_in[34];
  const float* bn2g = (const float*)d_in[35];
  const float* bn2b = (const float*)d_in[36];
  const float* bn2m = (const float*)d_in[37];
  const float* bn2v = (const float*)d_in[38];
  const float* gatewp = (const float*)d_in[39];
  const float* gatewc = (const float*)d_in[40];
  const float* gateb  = (const float*)d_in[41];
  const float* outwp  = (const float*)d_in[42];
  const float* outb   = (const float*)d_in[43];
  float* dout = (float*)d_out;

  char* ws = (char*)d_ws; size_t off = 0;
  auto alc = [&](size_t n)->char*{ char* p = ws + off; off = (off + n + 255) & ~(size_t)255; return p; };
  float* xg_f  = (float*)alc((size_t)128*80*1536*4);   // dead after sentence scan
  float* xg_b  = (float*)alc((size_t)128*80*1536*4);   // (bf16 packs + Y0/Y1 alias here)
  float* xg_cf = (float*)alc((size_t)128*6*1536*4);
  float* xg_cb = (float*)alc((size_t)128*6*1536*4);
  float* gh    = (float*)alc((size_t)2*128*1536*4); (void)gh;
  float* sent  = (float*)alc((size_t)128*80*1024*4);   // dead after par_cs0 (head packs alias)
  float* g_c   = (float*)alc((size_t)128*6*1024*4);
  u16*   sentT = (u16*)alc((size_t)128*1024*96*2);
  float* cv    = (float*)alc((size_t)128*1024*4);
  float* uu    = (float*)alc((size_t)128*1024*4);
  float* scb   = (float*)alc((size_t)128*80*4);
  float* aw    = (float*)alc((size_t)128*80*4);
  float* Cs0   = (float*)alc((size_t)128*2048*4);
  u16* W1p = (u16*)alc((size_t)3*1024*96*2);
  u16* W2p = (u16*)alc((size_t)3*1024*1024*2);
  u16* W3p = (u16*)alc((size_t)3*1024*1024*2);
  u16* W4p = (u16*)alc((size_t)3*1024*1024*2);
  float* ab  = (float*)alc((size_t)4*2048*4);
  u32*  Penc = (u32*)alc((size_t)128*1024*4);
  float* Pf  = (float*)alc((size_t)128*1024*4);
  float* t1  = (float*)alc((size_t)128*2048*4);
  float* t2  = (float*)alc((size_t)128*2048*4);
  u16* xbf_s = (u16*)alc((size_t)10240*320*2);
  u16* xbf_c = (u16*)alc((size_t)768*320*2);
  u16* Wsf = (u16*)alc((size_t)1536*320*2);
  u16* Wsb = (u16*)alc((size_t)1536*320*2);
  u16* Wcf = (u16*)alc((size_t)1536*320*2);
  u16* Wcb = (u16*)alc((size_t)1536*320*2);

  // --- aliased sub-regions (no new high-water allocation) ---
  char* R1 = (char*)xg_f;
  u16* linw_bf  = (u16*)(R1);                      // 12,582,912 B
  u16* attnw_bf = (u16*)(R1 + 12582912);           //  2,097,152 B
  u16* gcbf     = (u16*)(R1 + 14680064);           //  1,572,864 B
  u16* cvbf     = (u16*)(R1 + 16252928);           //    262,144 B
  const int bc = 16;
  u16* Y0 = (u16*)(R1 + 16515072);                 // 33,554,432 B
  u16* Y1 = Y0 + (size_t)bc*1024*1024;             // 33,554,432 B
  char* R2 = (char*)sent;
  u16* gwp_bf = (u16*)(R2);                        // 4,194,304 B
  u16* gwc_bf = (u16*)(R2 + 4194304);              // 8,388,608 B
  u16* owp_bf = (u16*)(R2 + 12582912);             // 4,194,304 B
  u16* Pfbf   = (u16*)(R2 + 16777216);             //   262,144 B
  u16* Cs0bf  = (u16*)(R2 + 17039360);             //   524,288 B

  dim3 T(256), T5(512);

  // ---- prep ----
  pack_w<<<dim3((3*1024*96+255)/256), T, 0, stream>>>(c11w, W1p, 1024, 80, 96);
  pack_w<<<dim3((3*1024*1024+255)/256), T, 0, stream>>>(c13w, W2p, 1024, 1024, 1024);
  pack_w<<<dim3((3*1024*1024+255)/256), T, 0, stream>>>(c21w, W3p, 1024, 1024, 1024);
  pack_w<<<dim3((3*1024*1024+255)/256), T, 0, stream>>>(c23w, W4p, 1024, 1024, 1024);
  pack_wk<<<dim3((1536*320+255)/256), T, 0, stream>>>(sgwihf, Wsf, 1536, 300, 320);
  pack_wk<<<dim3((1536*320+255)/256), T, 0, stream>>>(sgwihb, Wsb, 1536, 300, 320);
  pack_wk<<<dim3((1536*320+255)/256), T, 0, stream>>>(cgwihf, Wcf, 1536, 300, 320);
  pack_wk<<<dim3((1536*320+255)/256), T, 0, stream>>>(cgwihb, Wcb, 1536, 300, 320);
  pack_x<<<dim3((10240*320+255)/256), T, 0, stream>>>(emb, input_batch, 80, 80, xbf_s, 10240);
  pack_x<<<dim3((768*320+255)/256), T, 0, stream>>>(emb, choices, 6, 24, xbf_c, 768);
  prep_ab<<<16, T, 0, stream>>>(c11b, c13b, c21b, c23b,
                                bn1g,bn1b,bn1m,bn1v, bn2g,bn2b,bn2m,bn2v, ab);
  init_penc<<<512, T, 0, stream>>>(Penc);

  // ---- input-gate GEMMs (bf16 MFMA), fwd+bwd via grid.z ----
  gemm_bf16<<<dim3(80,12,2), T, 0, stream>>>(Wsf, Wsb, xbf_s, sgbihf, sgbihb,
                                             xg_f, xg_b, 1536, 320, 10);
  gemm_bf16<<<dim3(6,12,2), T, 0, stream>>>(Wcf, Wcb, xbf_c, cgbihf, cgbihb,
                                            xg_cf, xg_cb, 1536, 320, 10);

  // ---- BiGRU scans ----
  for (int t = 0; t < 80; ++t)
    gru_step<<<dim3(32,4,2), T, 0, stream>>>(xg_f, xg_b, sgwhhf, sgwhhb,
                                             sgbhhf, sgbhhb, sent, 80, t);
  for (int t = 0; t < 6; ++t)
    gru_step<<<dim3(32,4,2), T, 0, stream>>>(xg_cf, xg_cb, cgwhhf, cgwhhb,
                                             cgbhhf, cgbhhb, g_c, 6, t);

  // ---- bf16 packs for lin/attn (xg region now dead) ----
  pack_wk<<<dim3((1024*6144+255)/256), T, 0, stream>>>(lin_w, linw_bf, 1024, 6144, 6144);
  pack_wk<<<dim3((1024*1024+255)/256), T, 0, stream>>>(attn_w, attnw_bf, 1024, 1024, 1024);
  pack_f2b<<<dim3((128*6144+255)/256), T, 0, stream>>>(g_c, gcbf, 128*6144);

  transpose_sent<<<dim3(16,128), T, 0, stream>>>(sent, sentT);

  // ---- choice vector (split-K bf16) + attention ----
  initc<<<dim3((128*1024+255)/256), T, 0, stream>>>(cv, lin_b, 128*1024, 1023);
  gemm_bf16_sk<<<dim3(1,8,6), T, 0, stream>>>(linw_bf, gcbf, cv, 1024, 6144, 32);
  pack_f2b<<<dim3((128*1024+255)/256), T, 0, stream>>>(cv, cvbf, 128*1024);
  initc<<<dim3((128*1024+255)/256), T, 0, stream>>>(uu, nullptr, 128*1024, 1023);
  gemm_bf16_sk<<<dim3(1,8,2), T, 0, stream>>>(attnw_bf, cvbf, uu, 1024, 1024, 16);
  attn_scores<<<2560, T, 0, stream>>>(sent, uu, attn_b, scb);
  softmax80<<<128, dim3(64), 0, stream>>>(scb, aw);
  par_cs0<<<128, T, 0, stream>>>(aw, sent, cv, Cs0);

  // ---- head weight/activation packs (sent region now dead) ----
  pack_wk<<<dim3((2048*1024+255)/256), T, 0, stream>>>(gatewp, gwp_bf, 2048, 1024, 1024);
  pack_wk<<<dim3((2048*2048+255)/256), T, 0, stream>>>(gatewc, gwc_bf, 2048, 2048, 2048);
  pack_wk<<<dim3((2048*1024+255)/256), T, 0, stream>>>(outwp, owp_bf, 2048, 1024, 1024);
  pack_f2b<<<dim3((128*2048+255)/256), T, 0, stream>>>(Cs0, Cs0bf, 128*2048);

  // ---- conv stack (bf16 MFMA, 256x256 tiles, counted-vmcnt pipeline) ----
  for (int b0 = 0; b0 < 128; b0 += bc){
    conv_mfma<<<dim3(4,4,bc), T5, 0, stream>>>(sentT + (size_t)b0*1024*96, (long)1024*96,
        W1p, ab+0,    ab+1024, Y0, (long)1024*1024, nullptr, 0, 1024, 1022, 96,   1, 3,  0);
    conv_mfma<<<dim3(4,4,bc), T5, 0, stream>>>(Y0, (long)1024*1024,
        W2p, ab+2048, ab+3072, Y1, (long)1024*1024, nullptr, 0, 1022, 1016, 1024, 3, 32, 1);
    conv_mfma<<<dim3(4,4,bc), T5, 0, stream>>>(Y1, (long)1024*1024,
        W3p, ab+4096, ab+5120, Y0, (long)1024*1024, nullptr, 0, 1016, 1014, 1024, 1, 32, 0);
    conv_mfma<<<dim3(4,4,bc), T5, 0, stream>>>(Y0, (long)1024*1024,
        W4p, ab+6144, ab+7168, nullptr, 0, Penc, b0,          1014, 1008, 1024, 3, 32, 2);
  }
  dec_p<<<512, T, 0, stream>>>(Penc, Pf);
  pack_f2b<<<dim3((128*1024+255)/256), T, 0, stream>>>(Pf, Pfbf, 128*1024);

  // ---- head (split-K bf16) ----
  initc<<<dim3((128*2048+255)/256), T, 0, stream>>>(t1, gateb, 128*2048, 2047);
  gemm_bf16_sk<<<dim3(1,16,2), T, 0, stream>>>(gwp_bf, Pfbf, t1, 2048, 1024, 16);
  gemm_bf16_sk<<<dim3(1,16,4), T, 0, stream>>>(gwc_bf, Cs0bf, t1, 2048, 2048, 16);
  initc<<<dim3((128*2048+255)/256), T, 0, stream>>>(t2, nullptr, 128*2048, 2047);
  gemm_bf16_sk<<<dim3(1,16,2), T, 0, stream>>>(owp_bf, Pfbf, t2, 2048, 1024, 16);
  head_final<<<128, T, 0, stream>>>(Cs0, t1, t2, outb, dout);
}

// Round 7
// 3863.503 us; speedup vs baseline: 1.0304x; 1.0304x over previous
//
#include <hip/hip_runtime.h>

typedef unsigned int u32;
typedef unsigned short u16;
typedef __attribute__((ext_vector_type(4))) float f32x4;
typedef __attribute__((ext_vector_type(8))) short bf16x8;

#define DEV static __device__ __forceinline__

DEV float sigf(float x){ return 1.0f/(1.0f + expf(-x)); }

DEV u16 f2bf(float x){
  u32 u = __float_as_uint(x);
  u32 r = (u + 0x7FFFu + ((u >> 16) & 1u)) >> 16;
  return (u16)r;
}

DEV u32 encf(float f){
  u32 u = __float_as_uint(f);
  return (u & 0x80000000u) ? ~u : (u | 0x80000000u);
}
DEV float decf(u32 e){
  return (e & 0x80000000u) ? __uint_as_float(e ^ 0x80000000u) : __uint_as_float(~e);
}

DEV void gload16(const void* g, void* l){
  __builtin_amdgcn_global_load_lds((const __attribute__((address_space(1))) u32*)g,
                                   (__attribute__((address_space(3))) u32*)l, 16, 0, 0);
}

// ---------------------------------------------------------------------------
// bf16 MFMA GEMM: C[n][m] = sum_k A[m][k]*B[n][k] + bias[m]  (f32 out)
// Tiles 128x128, BK=32. Dual weights via grid.z. (input-gate GEMMs)
// ---------------------------------------------------------------------------
__global__ __launch_bounds__(256,2) void gemm_bf16(
    const u16* __restrict__ A, const u16* __restrict__ A2,
    const u16* __restrict__ B,
    const float* __restrict__ bias, const float* __restrict__ bias2,
    float* __restrict__ C, float* __restrict__ C2, int ldc,
    int Kp, int ksteps)
{
  __shared__ u16 lds[(128 + 128)*32];
  char* ldsc = (char*)&lds[0];
  const int Boff = 128*64;
  const int tid = threadIdx.x;
  const int l = tid & 63, w = tid >> 6;
  const int n0 = blockIdx.x * 128, m0 = blockIdx.y * 128;
  const u16* Ause = blockIdx.z ? A2 : A;
  const float* buse = blockIdx.z ? bias2 : bias;
  float* Cuse = blockIdx.z ? C2 : C;
  const int wr = w >> 1, wc = w & 1;
  const int lr = l & 15, g = l >> 4;

  f32x4 acc[4][4];
  #pragma unroll
  for (int i=0;i<4;++i)
    #pragma unroll
    for (int j=0;j<4;++j) acc[i][j] = f32x4{0.f,0.f,0.f,0.f};

  for (int ks = 0; ks < ksteps; ++ks) {
    const int i0 = ks*32;
    __syncthreads();
    #pragma unroll
    for (int r = 0; r < 2; ++r) {
      const int rr = w*2 + r;
      const int c = rr*64 + l;
      const int row = c >> 2, bpos = c & 3;
      const int ib = bpos ^ ((row>>1) & 3);
      gload16(Ause + ((size_t)(m0 + row)*Kp + (i0 + ib*8)), ldsc + rr*1024);
      gload16(B    + ((size_t)(n0 + row)*Kp + (i0 + ib*8)), ldsc + Boff + rr*1024);
    }
    __syncthreads();
    bf16x8 af[4], bfr[4];
    #pragma unroll
    for (int m=0;m<4;++m){
      int o = wr*64 + m*16 + lr;
      af[m] = *(const bf16x8*)(ldsc + o*64 + ((g ^ ((o>>1)&3))<<4));
    }
    #pragma unroll
    for (int n=0;n<4;++n){
      int pr = wc*64 + n*16 + lr;
      bfr[n] = *(const bf16x8*)(ldsc + Boff + pr*64 + ((g ^ ((pr>>1)&3))<<4));
    }
    #pragma unroll
    for (int m=0;m<4;++m)
      #pragma unroll
      for (int n=0;n<4;++n)
        acc[m][n] = __builtin_amdgcn_mfma_f32_16x16x32_bf16(af[m], bfr[n], acc[m][n], 0,0,0);
  }

  #pragma unroll
  for (int m=0;m<4;++m){
    int mm = m0 + wr*64 + m*16 + g*4;
    f32x4 bv = *(const f32x4*)(buse + mm);
    #pragma unroll
    for (int n=0;n<4;++n){
      int p = n0 + wc*64 + n*16 + lr;
      f32x4 v;
      #pragma unroll
      for (int r2=0;r2<4;++r2) v[r2] = acc[m][n][r2] + bv[r2];
      *(f32x4*)(Cuse + (size_t)p*ldc + mm) = v;
    }
  }
}

// ---------------------------------------------------------------------------
// bf16 MFMA GEMM, split-K, atomicAdd into pre-initialized f32 C.
// ---------------------------------------------------------------------------
__global__ __launch_bounds__(256,2) void gemm_bf16_sk(
    const u16* __restrict__ A, const u16* __restrict__ B,
    float* __restrict__ C, int ldc, int Kp, int kpc)
{
  __shared__ u16 lds[(128 + 128)*32];
  char* ldsc = (char*)&lds[0];
  const int Boff = 128*64;
  const int tid = threadIdx.x;
  const int l = tid & 63, w = tid >> 6;
  const int n0 = blockIdx.x * 128, m0 = blockIdx.y * 128;
  const int ks0 = blockIdx.z * kpc;
  const int wr = w >> 1, wc = w & 1;
  const int lr = l & 15, g = l >> 4;

  f32x4 acc[4][4];
  #pragma unroll
  for (int i=0;i<4;++i)
    #pragma unroll
    for (int j=0;j<4;++j) acc[i][j] = f32x4{0.f,0.f,0.f,0.f};

  for (int ks = 0; ks < kpc; ++ks) {
    const int i0 = (ks0 + ks)*32;
    __syncthreads();
    #pragma unroll
    for (int r = 0; r < 2; ++r) {
      const int rr = w*2 + r;
      const int c = rr*64 + l;
      const int row = c >> 2, bpos = c & 3;
      const int ib = bpos ^ ((row>>1) & 3);
      gload16(A + ((size_t)(m0 + row)*Kp + (i0 + ib*8)), ldsc + rr*1024);
      gload16(B + ((size_t)(n0 + row)*Kp + (i0 + ib*8)), ldsc + Boff + rr*1024);
    }
    __syncthreads();
    bf16x8 af[4], bfr[4];
    #pragma unroll
    for (int m=0;m<4;++m){
      int o = wr*64 + m*16 + lr;
      af[m] = *(const bf16x8*)(ldsc + o*64 + ((g ^ ((o>>1)&3))<<4));
    }
    #pragma unroll
    for (int n=0;n<4;++n){
      int pr = wc*64 + n*16 + lr;
      bfr[n] = *(const bf16x8*)(ldsc + Boff + pr*64 + ((g ^ ((pr>>1)&3))<<4));
    }
    #pragma unroll
    for (int m=0;m<4;++m)
      #pragma unroll
      for (int n=0;n<4;++n)
        acc[m][n] = __builtin_amdgcn_mfma_f32_16x16x32_bf16(af[m], bfr[n], acc[m][n], 0,0,0);
  }

  #pragma unroll
  for (int m=0;m<4;++m){
    int mm = m0 + wr*64 + m*16 + g*4;
    #pragma unroll
    for (int n=0;n<4;++n){
      int p = n0 + wc*64 + n*16 + lr;
      float* dst = C + (size_t)p*ldc + mm;
      #pragma unroll
      for (int r2=0;r2<4;++r2) atomicAdd(dst + r2, acc[m][n][r2]);
    }
  }
}

// C[i] = bias ? bias[i & mmask] : 0
__global__ void initc(float* __restrict__ C, const float* __restrict__ bias,
                      int total, int mmask)
{
  int i = blockIdx.x*256 + threadIdx.x;
  if (i < total) C[i] = bias ? bias[i & mmask] : 0.f;
}

// ---------------------------------------------------------------------------
// Fused GRU step (f32): gh = h_prev @ W_hh^T + b_hh, gates, h update.
// Grid (32 jg, 4 bg, 2 dir), 256 thr.
// ---------------------------------------------------------------------------
__global__ __launch_bounds__(256) void gru_step(
    const float* __restrict__ xg0, const float* __restrict__ xg1,
    const float* __restrict__ whh0, const float* __restrict__ whh1,
    const float* __restrict__ bhh0, const float* __restrict__ bhh1,
    float* __restrict__ hs, int S, int t)
{
  __shared__ float hL[32*520];
  __shared__ float wL[48*132];
  const int tid = threadIdx.x;
  const int tj = tid & 15, tb = tid >> 4;
  const int jg = blockIdx.x;
  const int b0 = blockIdx.y*32;
  const int dir = blockIdx.z;
  const int l = tid & 63, w = tid >> 6;
  const float* xg  = dir ? xg1  : xg0;
  const float* whh = dir ? whh1 : whh0;
  const float* bhh = dir ? bhh1 : bhh0;
  const int tt = dir ? (S-1-t) : t;
  const int j = jg*16 + tj;

  float accr[2], accz[2], accn[2];
  {
    float br = bhh[j], bz = bhh[512+j], bn = bhh[1024+j];
    accr[0]=br; accr[1]=br; accz[0]=bz; accz[1]=bz; accn[0]=bn; accn[1]=bn;
  }

  if (t > 0){
    const int tp = dir ? (tt+1) : (tt-1);
    #pragma unroll
    for (int rr = 0; rr < 8; ++rr){
      int row = w*8 + rr;
      const float* srcb = hs + ((size_t)(b0+row)*S + tp)*1024 + dir*512;
      gload16(srcb + l*4,       (char*)hL + (size_t)(row*520)*4);
      gload16(srcb + 256 + l*4, (char*)hL + (size_t)(row*520 + 256)*4);
    }
    for (int c = 0; c < 4; ++c){
      const int k0 = c*128;
      __syncthreads();
      #pragma unroll
      for (int i = 0; i < 6; ++i){
        int qidx = tid + i*256;
        int row = qidx >> 5, q = qidx & 31;
        int grow = (row>>4)*512 + jg*16 + (row & 15);
        f32x4 v = *(const f32x4*)(whh + (size_t)grow*512 + k0 + q*4);
        *(f32x4*)(wL + row*132 + q*4) = v;
      }
      __syncthreads();
      #pragma unroll 4
      for (int q = 0; q < 32; ++q){
        f32x4 ha  = *(const f32x4*)(hL + (2*tb  )*520 + k0 + q*4);
        f32x4 hb  = *(const f32x4*)(hL + (2*tb+1)*520 + k0 + q*4);
        f32x4 wr4 = *(const f32x4*)(wL + tj*132      + q*4);
        f32x4 wz4 = *(const f32x4*)(wL + (16+tj)*132 + q*4);
        f32x4 wn4 = *(const f32x4*)(wL + (32+tj)*132 + q*4);
        #pragma unroll
        for (int e = 0; e < 4; ++e){
          accr[0] += ha[e]*wr4[e]; accz[0] += ha[e]*wz4[e]; accn[0] += ha[e]*wn4[e];
          accr[1] += hb[e]*wr4[e]; accz[1] += hb[e]*wz4[e]; accn[1] += hb[e]*wn4[e];
        }
      }
    }
  }

  #pragma unroll
  for (int bi = 0; bi < 2; ++bi){
    int lb = 2*tb + bi;
    int b = b0 + lb;
    size_t xbase = ((size_t)b*S + tt)*1536;
    float gir = xg[xbase + j], giz = xg[xbase + 512 + j], gin = xg[xbase + 1024 + j];
    float hp = (t>0) ? hL[lb*520 + j] : 0.f;
    float r = sigf(gir + accr[bi]);
    float z = sigf(giz + accz[bi]);
    float n = tanhf(gin + r*accn[bi]);
    hs[((size_t)b*S + tt)*1024 + dir*512 + j] = (1.f - z)*n + z*hp;
  }
}

// sent [b][80][1024] f32 -> sentT [b][1024][96] bf16 (s in [80,96) zero pad)
__global__ void transpose_sent(const float* __restrict__ sent, u16* __restrict__ sentT)
{
  __shared__ float tl[80][65];
  int b = blockIdx.y, h0 = blockIdx.x*64;
  for (int idx = threadIdx.x; idx < 80*64; idx += 256){
    int s = idx >> 6, hh = idx & 63;
    tl[s][hh] = sent[((size_t)b*80 + s)*1024 + h0 + hh];
  }
  __syncthreads();
  for (int idx = threadIdx.x; idx < 64*96; idx += 256){
    int hh = idx / 96, s = idx % 96;
    sentT[((size_t)b*1024 + h0 + hh)*96 + s] = (s < 80) ? f2bf(tl[s][hh]) : (u16)0;
  }
}

__global__ void attn_scores(const float* __restrict__ sent, const float* __restrict__ u,
                            const float* __restrict__ attn_b, float* __restrict__ sc)
{
  int wid = blockIdx.x*4 + (threadIdx.x >> 6);
  int lane = threadIdx.x & 63;
  const float* row = sent + (size_t)wid*1024;
  const float* ub = u + (size_t)(wid/80)*1024;
  float acc = 0.f;
  for (int h = lane; h < 1024; h += 64) acc += row[h]*(ub[h] + attn_b[h]);
  #pragma unroll
  for (int m = 32; m; m >>= 1) acc += __shfl_xor(acc, m);
  if (lane == 0) sc[wid] = acc;
}

// one wave per batch row; 80 values over 64 lanes (lanes 0-15 carry 2)
__global__ void softmax80(const float* __restrict__ sc, float* __restrict__ a)
{
  int b = blockIdx.x, l = threadIdx.x;
  float v0 = sc[b*80 + l];
  float v1 = (l < 16) ? sc[b*80 + 64 + l] : -1e30f;
  float mx = fmaxf(v0, v1);
  #pragma unroll
  for (int m = 32; m; m >>= 1) mx = fmaxf(mx, __shfl_xor(mx, m));
  float e0 = expf(v0 - mx);
  float e1 = (l < 16) ? expf(v1 - mx) : 0.f;
  float s = e0 + e1;
  #pragma unroll
  for (int m = 32; m; m >>= 1) s += __shfl_xor(s, m);
  float inv = 1.f/s;
  a[b*80 + l] = e0*inv;
  if (l < 16) a[b*80 + 64 + l] = e1*inv;
}

__global__ void par_cs0(const float* __restrict__ a, const float* __restrict__ sent,
                        const float* __restrict__ cv, float* __restrict__ Cs0)
{
  int b = blockIdx.x;
  for (int h = threadIdx.x; h < 1024; h += 256){
    float acc = 0.f;
    for (int s = 0; s < 80; ++s) acc += a[b*80+s]*sent[((size_t)b*80+s)*1024 + h];
    Cs0[(size_t)b*2048 + 1024 + h] = acc;
    Cs0[(size_t)b*2048 + h] = cv[(size_t)b*1024 + h];
  }
}

// pack conv weight [O][CIs][3] f32 -> [3][O][CIp] bf16
__global__ void pack_w(const float* __restrict__ src, u16* __restrict__ dst,
                       int O, int CIs, int CIp)
{
  int i = blockIdx.x*256 + threadIdx.x;
  int total = 3*O*CIp;
  if (i >= total) return;
  int tap = i/(O*CIp); int rem = i%(O*CIp); int o = rem/CIp, ci = rem%CIp;
  float v = (ci < CIs) ? src[((size_t)o*CIs + ci)*3 + tap] : 0.f;
  dst[((size_t)tap*O + o)*CIp + ci] = f2bf(v);
}

// pack dense weight [M][Ks] f32 -> [M][Kp] bf16 (zero pad)
__global__ void pack_wk(const float* __restrict__ src, u16* __restrict__ dst,
                        int M, int Ks, int Kp)
{
  int i = blockIdx.x*256 + threadIdx.x;
  if (i >= M*Kp) return;
  int row = i/Kp, k = i%Kp;
  dst[i] = (k < Ks) ? f2bf(src[(size_t)row*Ks + k]) : (u16)0;
}

// elementwise f32 -> bf16
__global__ void pack_f2b(const float* __restrict__ src, u16* __restrict__ dst, int n)
{
  int i = blockIdx.x*256 + threadIdx.x;
  if (i < n) dst[i] = f2bf(src[i]);
}

// gather+pack embeddings: rows R, dst [R][320] bf16
__global__ void pack_x(const float* __restrict__ emb, const int* __restrict__ toks,
                       int rdiv, int rmul, u16* __restrict__ dst, int R)
{
  int i = blockIdx.x*256 + threadIdx.x;
  if (i >= R*320) return;
  int row = i/320, k = i%320;
  int tok = toks[(row/rdiv)*rmul + (row%rdiv)];
  dst[i] = (k < 300) ? f2bf(emb[(size_t)tok*300 + k]) : (u16)0;
}

__global__ void prep_ab(const float* c11b, const float* c13b, const float* c21b, const float* c23b,
                        const float* g1, const float* b1, const float* m1, const float* v1,
                        const float* g2, const float* b2, const float* m2, const float* v2,
                        float* ab)
{
  int i = blockIdx.x*256 + threadIdx.x;
  if (i >= 4096) return;
  int layer = i >> 10, o = i & 1023;
  float al, be;
  if (layer == 0){ al = g1[o]/sqrtf(v1[o]+1e-5f); be = c11b[o]*al + b1[o] - m1[o]*al; }
  else if (layer == 1){ al = 1.f; be = c13b[o]; }
  else if (layer == 2){ al = g2[o]/sqrtf(v2[o]+1e-5f); be = c21b[o]*al + b2[o] - m2[o]*al; }
  else { al = 1.f; be = c23b[o]; }
  ab[layer*2048 + o] = al;
  ab[layer*2048 + 1024 + o] = be;
}

__global__ void init_penc(u32* p){
  int i = blockIdx.x*256 + threadIdx.x;
  if (i < 128*1024) p[i] = encf(-3.3e38f);
}
__global__ void dec_p(const u32* __restrict__ pe, float* __restrict__ pf){
  int i = blockIdx.x*256 + threadIdx.x;
  if (i < 128*1024) pf[i] = decf(pe[i]);
}

// ---------------------------------------------------------------------------
// Conv as 3-tap MFMA GEMM, m201-style fine-phase pipeline.
// Tile 256o x 256p, 512 thr = 8 waves (2 wr x 4 wc), wave = 128o x 64p.
// 3 phases per K-step (one per tap). A: 4 LDS slots (depth-3 prefetch),
// B: 2 buffers (staged one K-step ahead at tap0). Phase skeleton:
//   ds_read 12 frags (staged 3 phases ago)  <- BEFORE stage issue
//   stage A(+B at tap0) for future phase
//   s_waitcnt vmcnt(N)  N = c(p)+c(p-1): tap0=7, tap1=7, tap2=4 (never 0)
//   s_barrier ; setprio(1) 32 MFMA setprio(0) ; s_barrier
// Final K-step phases use vmcnt(0) (loads fully aged - free drain).
// ---------------------------------------------------------------------------
#define CPHASE(KS, TAP, NSTR)                                                 \
  {                                                                           \
    char* Aslot = ldsc + ((((KS)*3 + (TAP)) & 3) << 14);                      \
    char* Bbuf  = ldsc + 65536 + (((KS)&1) ? 17408 : 0);                      \
    bf16x8 af[8], bfr[4];                                                     \
    _Pragma("unroll")                                                         \
    for (int m=0;m<8;++m){                                                    \
      int o = wr*128 + m*16 + lr;                                             \
      af[m] = *(const bf16x8*)(Aslot + o*64 + ((g ^ ((o>>1)&3))<<4));         \
    }                                                                         \
    _Pragma("unroll")                                                         \
    for (int n=0;n<4;++n){                                                    \
      int pr = wc*64 + n*16 + lr + dil*(TAP);                                 \
      bfr[n] = *(const bf16x8*)(Bbuf + pr*64 + ((g ^ ((pr>>1)&3))<<4));       \
    }                                                                         \
    if ((KS)+1 < ksteps) {                                                    \
      char* Adst = ldsc + ((((KS)*3 + (TAP) + 3) & 3) << 14);                 \
      const int i0n = ((KS)+1)*32;                                            \
      _Pragma("unroll")                                                       \
      for (int r = 0; r < 2; ++r) {                                           \
        const int c = r*512 + tid;                                            \
        const int row = c >> 2, bpos = c & 3;                                 \
        const int ib = bpos ^ ((row>>1) & 3);                                 \
        gload16(Wt + ((size_t)((TAP)*1024 + o0 + row)*CI + (i0n + ib*8)),     \
                Adst + (size_t)c*16);                                         \
      }                                                                       \
      if ((TAP) == 0) {                                                       \
        char* Bdst = ldsc + 65536 + ((((KS)+1)&1) ? 17408 : 0);               \
        _Pragma("unroll")                                                     \
        for (int r = 0; r < 2; ++r) {                                         \
          const int c = w*136 + r*64 + l;                                     \
          const int row = c >> 2, bpos = c & 3;                               \
          const int ib = bpos ^ ((row>>1) & 3);                               \
          int ps = p0 + row; ps = ps < P_in ? ps : (P_in - 1);                \
          gload16(Xb + ((size_t)ps*CI + (i0n + ib*8)), Bdst + (size_t)c*16);  \
        }                                                                     \
        if (l < 8) {                                                          \
          const int c = w*136 + 128 + l;                                      \
          const int row = c >> 2, bpos = c & 3;                               \
          const int ib = bpos ^ ((row>>1) & 3);                               \
          int ps = p0 + row; ps = ps < P_in ? ps : (P_in - 1);                \
          gload16(Xb + ((size_t)ps*CI + (i0n + ib*8)), Bdst + (size_t)c*16);  \
        }                                                                     \
      }                                                                       \
    }                                                                         \
    asm volatile("s_waitcnt vmcnt(" NSTR ")" ::: "memory");                   \
    __builtin_amdgcn_s_barrier();                                             \
    asm volatile("" ::: "memory");                                            \
    __builtin_amdgcn_s_setprio(1);                                            \
    _Pragma("unroll")                                                         \
    for (int n=0;n<4;++n)                                                     \
      _Pragma("unroll")                                                       \
      for (int m=0;m<8;++m)                                                   \
        acc[m][n] = __builtin_amdgcn_mfma_f32_16x16x32_bf16(af[m], bfr[n],    \
                                                            acc[m][n], 0,0,0);\
    __builtin_amdgcn_s_setprio(0);                                            \
    asm volatile("" ::: "memory");                                            \
    __builtin_amdgcn_s_barrier();                                             \
    asm volatile("" ::: "memory");                                            \
  }

__global__ __launch_bounds__(512,2) void conv_mfma(
    const u16* __restrict__ X, long bstrideX,
    const u16* __restrict__ Wt,
    const float* __restrict__ alpha, const float* __restrict__ beta,
    u16* __restrict__ Y, long bstrideY,
    u32* __restrict__ Penc, int b0,
    int P_in, int P_out, int CI, int dil, int ksteps, int mode)
{
  __shared__ u16 lds[50176];           // 100352 B: 4x16KB A slots + 2x17KB B
  char* ldsc = (char*)&lds[0];
  const int tid = threadIdx.x;
  const int l = tid & 63, w = tid >> 6;
  const int wg = blockIdx.x + (blockIdx.y<<2) + (blockIdx.z<<4);
  const int id2 = ((wg & 7) << 5) | (wg >> 3);       // XCD swizzle (bijective)
  const int p0 = (id2 & 3) * 256;
  const int o0 = ((id2 >> 2) & 3) * 256;
  const int bz = id2 >> 4;
  const u16* Xb = X + (size_t)bz * (size_t)bstrideX;
  const int wr = w >> 2, wc = w & 3;
  const int lr = l & 15, g = l >> 4;

  f32x4 acc[8][4];
  #pragma unroll
  for (int i=0;i<8;++i)
    #pragma unroll
    for (int j=0;j<4;++j) acc[i][j] = f32x4{0.f,0.f,0.f,0.f};

  // ---- prologue: stage A slots 0..2 (ks=0, taps 0..2) + B buf0 (ks=0) ----
  #pragma unroll
  for (int t = 0; t < 3; ++t){
    char* Adst = ldsc + (t << 14);
    #pragma unroll
    for (int r = 0; r < 2; ++r) {
      const int c = r*512 + tid;
      const int row = c >> 2, bpos = c & 3;
      const int ib = bpos ^ ((row>>1) & 3);
      gload16(Wt + ((size_t)(t*1024 + o0 + row)*CI + (ib*8)), Adst + (size_t)c*16);
    }
  }
  {
    char* Bdst = ldsc + 65536;
    #pragma unroll
    for (int r = 0; r < 2; ++r) {
      const int c = w*136 + r*64 + l;
      const int row = c >> 2, bpos = c & 3;
      const int ib = bpos ^ ((row>>1) & 3);
      int ps = p0 + row; ps = ps < P_in ? ps : (P_in - 1);
      gload16(Xb + ((size_t)ps*CI + (ib*8)), Bdst + (size_t)c*16);
    }
    if (l < 8) {
      const int c = w*136 + 128 + l;
      const int row = c >> 2, bpos = c & 3;
      const int ib = bpos ^ ((row>>1) & 3);
      int ps = p0 + row; ps = ps < P_in ? ps : (P_in - 1);
      gload16(Xb + ((size_t)ps*CI + (ib*8)), Bdst + (size_t)c*16);
    }
  }
  asm volatile("s_waitcnt vmcnt(0)" ::: "memory");
  __builtin_amdgcn_s_barrier();
  asm volatile("" ::: "memory");

  // ---- main: steady K-steps with counted vmcnt; final K-step drains ----
  for (int ks = 0; ks < ksteps-1; ++ks) {
    CPHASE(ks, 0, "7")
    CPHASE(ks, 1, "7")
    CPHASE(ks, 2, "4")
  }
  {
    const int ks = ksteps-1;
    CPHASE(ks, 0, "0")
    CPHASE(ks, 1, "0")
    CPHASE(ks, 2, "0")
  }

  if (mode == 2) {
    #pragma unroll
    for (int m=0;m<8;++m){
      int oo = o0 + wr*128 + m*16 + g*4;
      f32x4 al = *(const f32x4*)(alpha + oo);
      f32x4 be = *(const f32x4*)(beta + oo);
      float vm[4] = {-1e30f,-1e30f,-1e30f,-1e30f};
      #pragma unroll
      for (int n=0;n<4;++n){
        int p = p0 + wc*64 + n*16 + lr;
        bool ok = p < P_out;
        #pragma unroll
        for (int r2=0;r2<4;++r2){
          float v = acc[m][n][r2]*al[r2] + be[r2];
          vm[r2] = ok ? fmaxf(vm[r2], v) : vm[r2];
        }
      }
      #pragma unroll
      for (int r2=0;r2<4;++r2){
        float v = vm[r2];
        #pragma unroll
        for (int mask=1; mask<16; mask<<=1) v = fmaxf(v, __shfl_xor(v, mask));
        if (lr == 0) atomicMax(&Penc[(size_t)(b0+bz)*1024 + oo + r2], encf(v));
      }
    }
  } else {
    #pragma unroll
    for (int m=0;m<8;++m){
      int oo = o0 + wr*128 + m*16 + g*4;
      f32x4 al = *(const f32x4*)(alpha + oo);
      f32x4 be = *(const f32x4*)(beta + oo);
      #pragma unroll
      for (int n=0;n<4;++n){
        int p = p0 + wc*64 + n*16 + lr;
        if (p < P_out){
          float v0 = acc[m][n][0]*al[0] + be[0];
          float v1 = acc[m][n][1]*al[1] + be[1];
          float v2 = acc[m][n][2]*al[2] + be[2];
          float v3 = acc[m][n][3]*al[3] + be[3];
          if (mode == 0){ v0=fmaxf(v0,0.f); v1=fmaxf(v1,0.f); v2=fmaxf(v2,0.f); v3=fmaxf(v3,0.f); }
          uint2 pk;
          pk.x = (u32)f2bf(v0) | ((u32)f2bf(v1) << 16);
          pk.y = (u32)f2bf(v2) | ((u32)f2bf(v3) << 16);
          *(uint2*)(Y + (size_t)bz*(size_t)bstrideY + (size_t)p*1024 + oo) = pk;
        }
      }
    }
  }
}

__global__ void head_final(const float* __restrict__ Cs0, const float* __restrict__ t1,
                           const float* __restrict__ t2, const float* __restrict__ outb,
                           float* __restrict__ dout)
{
  __shared__ float red[256];
  int b = blockIdx.x;
  float part = 0.f;
  for (int gg = threadIdx.x; gg < 2048; gg += 256){
    float cd = Cs0[(size_t)b*2048+gg] * sigf(t1[(size_t)b*2048+gg]);
    part += cd * (t2[(size_t)b*2048+gg] + outb[gg]);
  }
  red[threadIdx.x] = part;
  __syncthreads();
  for (int s = 128; s > 0; s >>= 1){
    if (threadIdx.x < s) red[threadIdx.x] += red[threadIdx.x + s];
    __syncthreads();
  }
  if (threadIdx.x < 4) dout[b*4 + threadIdx.x] = red[0];
}

// ---------------------------------------------------------------------------
extern "C" void kernel_launch(void* const* d_in, const int* in_sizes, int n_in,
                              void* d_out, int out_size, void* d_ws, size_t ws_size,
                              hipStream_t stream)
{
  (void)in_sizes; (void)n_in; (void)out_size; (void)ws_size;
  const int*   input_batch = (const int*)d_in[0];
  const int*   choices     = (const int*)d_in[1];
  const float* emb    = (const float*)d_in[2];
  const float* sgwihf = (const float*)d_in[3];
  const float* sgwhhf = (const float*)d_in[4];
  const float* sgbihf = (const float*)d_in[5];
  const float* sgbhhf = (const float*)d_in[6];
  const float* sgwihb = (const float*)d_in[7];
  const float* sgwhhb = (const float*)d_in[8];
  const float* sgbihb = (const float*)d_in[9];
  const float* sgbhhb = (const float*)d_in[10];
  const float* cgwihf = (const float*)d_in[11];
  const float* cgwhhf = (const float*)d_in[12];
  const float* cgbihf = (const float*)d_in[13];
  const float* cgbhhf = (const float*)d_in[14];
  const float* cgwihb = (const float*)d_in[15];
  const float* cgwhhb = (const float*)d_in[16];
  const float* cgbihb = (const float*)d_in[17];
  const float* cgbhhb = (const float*)d_in[18];
  const float* lin_w  = (const float*)d_in[19];
  const float* lin_b  = (const float*)d_in[20];
  const float* attn_w = (const float*)d_in[21];
  const float* attn_b = (const float*)d_in[22];
  const float* c11w = (const float*)d_in[23];
  const float* c11b = (const float*)d_in[24];
  const float* c13w = (const float*)d_in[25];
  const float* c13b = (const float*)d_in[26];
  const float* c21w = (const float*)d_in[27];
  const float* c21b = (const float*)d_in[28];
  const float* c23w = (const float*)d_in[29];
  const float* c23b = (const float*)d_in[30];
  const float* bn1g = (const float*)d_in[31];
  const float* bn1b = (const float*)d_in[32];
  const float* bn1m = (const float*)d_in[33];
  const float* bn1v = (const float*)d_in[34];
  const float* bn2g = (const float*)d_in[35];
  const float* bn2b = (const float*)d_in[36];
  const float* bn2m = (const float*)d_in[37];
  const float* bn2v = (const float*)d_in[38];
  const float* gatewp = (const float*)d_in[39];
  const float* gatewc = (const float*)d_in[40];
  const float* gateb  = (const float*)d_in[41];
  const float* outwp  = (const float*)d_in[42];
  const float* outb   = (const float*)d_in[43];
  float* dout = (float*)d_out;

  char* ws = (char*)d_ws; size_t off = 0;
  auto alc = [&](size_t n)->char*{ char* p = ws + off; off = (off + n + 255) & ~(size_t)255; return p; };
  float* xg_f  = (float*)alc((size_t)128*80*1536*4);   // dead after sentence scan
  float* xg_b  = (float*)alc((size_t)128*80*1536*4);   // (bf16 packs + Y0/Y1 alias here)
  float* xg_cf = (float*)alc((size_t)128*6*1536*4);
  float* xg_cb = (float*)alc((size_t)128*6*1536*4);
  float* gh    = (float*)alc((size_t)2*128*1536*4); (void)gh;
  float* sent  = (float*)alc((size_t)128*80*1024*4);   // dead after par_cs0 (head packs alias)
  float* g_c   = (float*)alc((size_t)128*6*1024*4);
  u16*   sentT = (u16*)alc((size_t)128*1024*96*2);
  float* cv    = (float*)alc((size_t)128*1024*4);
  float* uu    = (float*)alc((size_t)128*1024*4);
  float* scb   = (float*)alc((size_t)128*80*4);
  float* aw    = (float*)alc((size_t)128*80*4);
  float* Cs0   = (float*)alc((size_t)128*2048*4);
  u16* W1p = (u16*)alc((size_t)3*1024*96*2);
  u16* W2p = (u16*)alc((size_t)3*1024*1024*2);
  u16* W3p = (u16*)alc((size_t)3*1024*1024*2);
  u16* W4p = (u16*)alc((size_t)3*1024*1024*2);
  float* ab  = (float*)alc((size_t)4*2048*4);
  u32*  Penc = (u32*)alc((size_t)128*1024*4);
  float* Pf  = (float*)alc((size_t)128*1024*4);
  float* t1  = (float*)alc((size_t)128*2048*4);
  float* t2  = (float*)alc((size_t)128*2048*4);
  u16* xbf_s = (u16*)alc((size_t)10240*320*2);
  u16* xbf_c = (u16*)alc((size_t)768*320*2);
  u16* Wsf = (u16*)alc((size_t)1536*320*2);
  u16* Wsb = (u16*)alc((size_t)1536*320*2);
  u16* Wcf = (u16*)alc((size_t)1536*320*2);
  u16* Wcb = (u16*)alc((size_t)1536*320*2);

  // --- aliased sub-regions (no new high-water allocation) ---
  char* R1 = (char*)xg_f;
  u16* linw_bf  = (u16*)(R1);                      // 12,582,912 B
  u16* attnw_bf = (u16*)(R1 + 12582912);           //  2,097,152 B
  u16* gcbf     = (u16*)(R1 + 14680064);           //  1,572,864 B
  u16* cvbf     = (u16*)(R1 + 16252928);           //    262,144 B
  const int bc = 16;
  u16* Y0 = (u16*)(R1 + 16515072);                 // 33,554,432 B
  u16* Y1 = Y0 + (size_t)bc*1024*1024;             // 33,554,432 B
  char* R2 = (char*)sent;
  u16* gwp_bf = (u16*)(R2);                        // 4,194,304 B
  u16* gwc_bf = (u16*)(R2 + 4194304);              // 8,388,608 B
  u16* owp_bf = (u16*)(R2 + 12582912);             // 4,194,304 B
  u16* Pfbf   = (u16*)(R2 + 16777216);             //   262,144 B
  u16* Cs0bf  = (u16*)(R2 + 17039360);             //   524,288 B

  dim3 T(256), T5(512);

  // ---- prep ----
  pack_w<<<dim3((3*1024*96+255)/256), T, 0, stream>>>(c11w, W1p, 1024, 80, 96);
  pack_w<<<dim3((3*1024*1024+255)/256), T, 0, stream>>>(c13w, W2p, 1024, 1024, 1024);
  pack_w<<<dim3((3*1024*1024+255)/256), T, 0, stream>>>(c21w, W3p, 1024, 1024, 1024);
  pack_w<<<dim3((3*1024*1024+255)/256), T, 0, stream>>>(c23w, W4p, 1024, 1024, 1024);
  pack_wk<<<dim3((1536*320+255)/256), T, 0, stream>>>(sgwihf, Wsf, 1536, 300, 320);
  pack_wk<<<dim3((1536*320+255)/256), T, 0, stream>>>(sgwihb, Wsb, 1536, 300, 320);
  pack_wk<<<dim3((1536*320+255)/256), T, 0, stream>>>(cgwihf, Wcf, 1536, 300, 320);
  pack_wk<<<dim3((1536*320+255)/256), T, 0, stream>>>(cgwihb, Wcb, 1536, 300, 320);
  pack_x<<<dim3((10240*320+255)/256), T, 0, stream>>>(emb, input_batch, 80, 80, xbf_s, 10240);
  pack_x<<<dim3((768*320+255)/256), T, 0, stream>>>(emb, choices, 6, 24, xbf_c, 768);
  prep_ab<<<16, T, 0, stream>>>(c11b, c13b, c21b, c23b,
                                bn1g,bn1b,bn1m,bn1v, bn2g,bn2b,bn2m,bn2v, ab);
  init_penc<<<512, T, 0, stream>>>(Penc);

  // ---- input-gate GEMMs (bf16 MFMA), fwd+bwd via grid.z ----
  gemm_bf16<<<dim3(80,12,2), T, 0, stream>>>(Wsf, Wsb, xbf_s, sgbihf, sgbihb,
                                             xg_f, xg_b, 1536, 320, 10);
  gemm_bf16<<<dim3(6,12,2), T, 0, stream>>>(Wcf, Wcb, xbf_c, cgbihf, cgbihb,
                                            xg_cf, xg_cb, 1536, 320, 10);

  // ---- BiGRU scans ----
  for (int t = 0; t < 80; ++t)
    gru_step<<<dim3(32,4,2), T, 0, stream>>>(xg_f, xg_b, sgwhhf, sgwhhb,
                                             sgbhhf, sgbhhb, sent, 80, t);
  for (int t = 0; t < 6; ++t)
    gru_step<<<dim3(32,4,2), T, 0, stream>>>(xg_cf, xg_cb, cgwhhf, cgwhhb,
                                             cgbhhf, cgbhhb, g_c, 6, t);

  // ---- bf16 packs for lin/attn (xg region now dead) ----
  pack_wk<<<dim3((1024*6144+255)/256), T, 0, stream>>>(lin_w, linw_bf, 1024, 6144, 6144);
  pack_wk<<<dim3((1024*1024+255)/256), T, 0, stream>>>(attn_w, attnw_bf, 1024, 1024, 1024);
  pack_f2b<<<dim3((128*6144+255)/256), T, 0, stream>>>(g_c, gcbf, 128*6144);

  transpose_sent<<<dim3(16,128), T, 0, stream>>>(sent, sentT);

  // ---- choice vector (split-K bf16) + attention ----
  initc<<<dim3((128*1024+255)/256), T, 0, stream>>>(cv, lin_b, 128*1024, 1023);
  gemm_bf16_sk<<<dim3(1,8,6), T, 0, stream>>>(linw_bf, gcbf, cv, 1024, 6144, 32);
  pack_f2b<<<dim3((128*1024+255)/256), T, 0, stream>>>(cv, cvbf, 128*1024);
  initc<<<dim3((128*1024+255)/256), T, 0, stream>>>(uu, nullptr, 128*1024, 1023);
  gemm_bf16_sk<<<dim3(1,8,2), T, 0, stream>>>(attnw_bf, cvbf, uu, 1024, 1024, 16);
  attn_scores<<<2560, T, 0, stream>>>(sent, uu, attn_b, scb);
  softmax80<<<128, dim3(64), 0, stream>>>(scb, aw);
  par_cs0<<<128, T, 0, stream>>>(aw, sent, cv, Cs0);

  // ---- head weight/activation packs (sent region now dead) ----
  pack_wk<<<dim3((2048*1024+255)/256), T, 0, stream>>>(gatewp, gwp_bf, 2048, 1024, 1024);
  pack_wk<<<dim3((2048*2048+255)/256), T, 0, stream>>>(gatewc, gwc_bf, 2048, 2048, 2048);
  pack_wk<<<dim3((2048*1024+255)/256), T, 0, stream>>>(outwp, owp_bf, 2048, 1024, 1024);
  pack_f2b<<<dim3((128*2048+255)/256), T, 0, stream>>>(Cs0, Cs0bf, 128*2048);

  // ---- conv stack (bf16 MFMA, 256x256 tiles, 3-phase pipelined) ----
  for (int b0 = 0; b0 < 128; b0 += bc){
    conv_mfma<<<dim3(4,4,bc), T5, 0, stream>>>(sentT + (size_t)b0*1024*96, (long)1024*96,
        W1p, ab+0,    ab+1024, Y0, (long)1024*1024, nullptr, 0, 1024, 1022, 96,   1, 3,  0);
    conv_mfma<<<dim3(4,4,bc), T5, 0, stream>>>(Y0, (long)1024*1024,
        W2p, ab+2048, ab+3072, Y1, (long)1024*1024, nullptr, 0, 1022, 1016, 1024, 3, 32, 1);
    conv_mfma<<<dim3(4,4,bc), T5, 0, stream>>>(Y1, (long)1024*1024,
        W3p, ab+4096, ab+5120, Y0, (long)1024*1024, nullptr, 0, 1016, 1014, 1024, 1, 32, 0);
    conv_mfma<<<dim3(4,4,bc), T5, 0, stream>>>(Y0, (long)1024*1024,
        W4p, ab+6144, ab+7168, nullptr, 0, Penc, b0,          1014, 1008, 1024, 3, 32, 2);
  }
  dec_p<<<512, T, 0, stream>>>(Penc, Pf);
  pack_f2b<<<dim3((128*1024+255)/256), T, 0, stream>>>(Pf, Pfbf, 128*1024);

  // ---- head (split-K bf16) ----
  initc<<<dim3((128*2048+255)/256), T, 0, stream>>>(t1, gateb, 128*2048, 2047);
  gemm_bf16_sk<<<dim3(1,16,2), T, 0, stream>>>(gwp_bf, Pfbf, t1, 2048, 1024, 16);
  gemm_bf16_sk<<<dim3(1,16,4), T, 0, stream>>>(gwc_bf, Cs0bf, t1, 2048, 2048, 16);
  initc<<<dim3((128*2048+255)/256), T, 0, stream>>>(t2, nullptr, 128*2048, 2047);
  gemm_bf16_sk<<<dim3(1,16,2), T, 0, stream>>>(owp_bf, Pfbf, t2, 2048, 1024, 16);
  head_final<<<128, T, 0, stream>>>(Cs0, t1, t2, outb, dout);
}

// Round 8
// 3745.292 us; speedup vs baseline: 1.0629x; 1.0316x over previous
//
#include <hip/hip_runtime.h>

typedef unsigned int u32;
typedef unsigned short u16;
typedef __attribute__((ext_vector_type(4))) float f32x4;
typedef __attribute__((ext_vector_type(8))) short bf16x8;

#define DEV static __device__ __forceinline__

DEV float sigf(float x){ return 1.0f/(1.0f + expf(-x)); }

DEV u16 f2bf(float x){
  u32 u = __float_as_uint(x);
  u32 r = (u + 0x7FFFu + ((u >> 16) & 1u)) >> 16;
  return (u16)r;
}

DEV u32 encf(float f){
  u32 u = __float_as_uint(f);
  return (u & 0x80000000u) ? ~u : (u | 0x80000000u);
}
DEV float decf(u32 e){
  return (e & 0x80000000u) ? __uint_as_float(e ^ 0x80000000u) : __uint_as_float(~e);
}

DEV void gload16(const void* g, void* l){
  __builtin_amdgcn_global_load_lds((const __attribute__((address_space(1))) u32*)g,
                                   (__attribute__((address_space(3))) u32*)l, 16, 0, 0);
}

// ---------------------------------------------------------------------------
// bf16 MFMA GEMM: C[n][m] = sum_k A[m][k]*B[n][k] + bias[m]  (f32 out)
// Tiles 128x128, BK=32. Dual weights via grid.z. (input-gate GEMMs)
// ---------------------------------------------------------------------------
__global__ __launch_bounds__(256,2) void gemm_bf16(
    const u16* __restrict__ A, const u16* __restrict__ A2,
    const u16* __restrict__ B,
    const float* __restrict__ bias, const float* __restrict__ bias2,
    float* __restrict__ C, float* __restrict__ C2, int ldc,
    int Kp, int ksteps)
{
  __shared__ u16 lds[(128 + 128)*32];
  char* ldsc = (char*)&lds[0];
  const int Boff = 128*64;
  const int tid = threadIdx.x;
  const int l = tid & 63, w = tid >> 6;
  const int n0 = blockIdx.x * 128, m0 = blockIdx.y * 128;
  const u16* Ause = blockIdx.z ? A2 : A;
  const float* buse = blockIdx.z ? bias2 : bias;
  float* Cuse = blockIdx.z ? C2 : C;
  const int wr = w >> 1, wc = w & 1;
  const int lr = l & 15, g = l >> 4;

  f32x4 acc[4][4];
  #pragma unroll
  for (int i=0;i<4;++i)
    #pragma unroll
    for (int j=0;j<4;++j) acc[i][j] = f32x4{0.f,0.f,0.f,0.f};

  for (int ks = 0; ks < ksteps; ++ks) {
    const int i0 = ks*32;
    __syncthreads();
    #pragma unroll
    for (int r = 0; r < 2; ++r) {
      const int rr = w*2 + r;
      const int c = rr*64 + l;
      const int row = c >> 2, bpos = c & 3;
      const int ib = bpos ^ ((row>>1) & 3);
      gload16(Ause + ((size_t)(m0 + row)*Kp + (i0 + ib*8)), ldsc + rr*1024);
      gload16(B    + ((size_t)(n0 + row)*Kp + (i0 + ib*8)), ldsc + Boff + rr*1024);
    }
    __syncthreads();
    bf16x8 af[4], bfr[4];
    #pragma unroll
    for (int m=0;m<4;++m){
      int o = wr*64 + m*16 + lr;
      af[m] = *(const bf16x8*)(ldsc + o*64 + ((g ^ ((o>>1)&3))<<4));
    }
    #pragma unroll
    for (int n=0;n<4;++n){
      int pr = wc*64 + n*16 + lr;
      bfr[n] = *(const bf16x8*)(ldsc + Boff + pr*64 + ((g ^ ((pr>>1)&3))<<4));
    }
    #pragma unroll
    for (int m=0;m<4;++m)
      #pragma unroll
      for (int n=0;n<4;++n)
        acc[m][n] = __builtin_amdgcn_mfma_f32_16x16x32_bf16(af[m], bfr[n], acc[m][n], 0,0,0);
  }

  #pragma unroll
  for (int m=0;m<4;++m){
    int mm = m0 + wr*64 + m*16 + g*4;
    f32x4 bv = *(const f32x4*)(buse + mm);
    #pragma unroll
    for (int n=0;n<4;++n){
      int p = n0 + wc*64 + n*16 + lr;
      f32x4 v;
      #pragma unroll
      for (int r2=0;r2<4;++r2) v[r2] = acc[m][n][r2] + bv[r2];
      *(f32x4*)(Cuse + (size_t)p*ldc + mm) = v;
    }
  }
}

// ---------------------------------------------------------------------------
// bf16 MFMA GEMM, split-K, atomicAdd into pre-initialized f32 C.
// ---------------------------------------------------------------------------
__global__ __launch_bounds__(256,2) void gemm_bf16_sk(
    const u16* __restrict__ A, const u16* __restrict__ B,
    float* __restrict__ C, int ldc, int Kp, int kpc)
{
  __shared__ u16 lds[(128 + 128)*32];
  char* ldsc = (char*)&lds[0];
  const int Boff = 128*64;
  const int tid = threadIdx.x;
  const int l = tid & 63, w = tid >> 6;
  const int n0 = blockIdx.x * 128, m0 = blockIdx.y * 128;
  const int ks0 = blockIdx.z * kpc;
  const int wr = w >> 1, wc = w & 1;
  const int lr = l & 15, g = l >> 4;

  f32x4 acc[4][4];
  #pragma unroll
  for (int i=0;i<4;++i)
    #pragma unroll
    for (int j=0;j<4;++j) acc[i][j] = f32x4{0.f,0.f,0.f,0.f};

  for (int ks = 0; ks < kpc; ++ks) {
    const int i0 = (ks0 + ks)*32;
    __syncthreads();
    #pragma unroll
    for (int r = 0; r < 2; ++r) {
      const int rr = w*2 + r;
      const int c = rr*64 + l;
      const int row = c >> 2, bpos = c & 3;
      const int ib = bpos ^ ((row>>1) & 3);
      gload16(A + ((size_t)(m0 + row)*Kp + (i0 + ib*8)), ldsc + rr*1024);
      gload16(B + ((size_t)(n0 + row)*Kp + (i0 + ib*8)), ldsc + Boff + rr*1024);
    }
    __syncthreads();
    bf16x8 af[4], bfr[4];
    #pragma unroll
    for (int m=0;m<4;++m){
      int o = wr*64 + m*16 + lr;
      af[m] = *(const bf16x8*)(ldsc + o*64 + ((g ^ ((o>>1)&3))<<4));
    }
    #pragma unroll
    for (int n=0;n<4;++n){
      int pr = wc*64 + n*16 + lr;
      bfr[n] = *(const bf16x8*)(ldsc + Boff + pr*64 + ((g ^ ((pr>>1)&3))<<4));
    }
    #pragma unroll
    for (int m=0;m<4;++m)
      #pragma unroll
      for (int n=0;n<4;++n)
        acc[m][n] = __builtin_amdgcn_mfma_f32_16x16x32_bf16(af[m], bfr[n], acc[m][n], 0,0,0);
  }

  #pragma unroll
  for (int m=0;m<4;++m){
    int mm = m0 + wr*64 + m*16 + g*4;
    #pragma unroll
    for (int n=0;n<4;++n){
      int p = n0 + wc*64 + n*16 + lr;
      float* dst = C + (size_t)p*ldc + mm;
      #pragma unroll
      for (int r2=0;r2<4;++r2) atomicAdd(dst + r2, acc[m][n][r2]);
    }
  }
}

// C[i] = bias ? bias[i & mmask] : 0
__global__ void initc(float* __restrict__ C, const float* __restrict__ bias,
                      int total, int mmask)
{
  int i = blockIdx.x*256 + threadIdx.x;
  if (i < total) C[i] = bias ? bias[i & mmask] : 0.f;
}

// ---------------------------------------------------------------------------
// Fused GRU step (f32): gh = h_prev @ W_hh^T + b_hh, gates, h update.
// Grid (32 jg, 4 bg, 2 dir), 256 thr.
// ---------------------------------------------------------------------------
__global__ __launch_bounds__(256) void gru_step(
    const float* __restrict__ xg0, const float* __restrict__ xg1,
    const float* __restrict__ whh0, const float* __restrict__ whh1,
    const float* __restrict__ bhh0, const float* __restrict__ bhh1,
    float* __restrict__ hs, int S, int t)
{
  __shared__ float hL[32*520];
  __shared__ float wL[48*132];
  const int tid = threadIdx.x;
  const int tj = tid & 15, tb = tid >> 4;
  const int jg = blockIdx.x;
  const int b0 = blockIdx.y*32;
  const int dir = blockIdx.z;
  const int l = tid & 63, w = tid >> 6;
  const float* xg  = dir ? xg1  : xg0;
  const float* whh = dir ? whh1 : whh0;
  const float* bhh = dir ? bhh1 : bhh0;
  const int tt = dir ? (S-1-t) : t;
  const int j = jg*16 + tj;

  float accr[2], accz[2], accn[2];
  {
    float br = bhh[j], bz = bhh[512+j], bn = bhh[1024+j];
    accr[0]=br; accr[1]=br; accz[0]=bz; accz[1]=bz; accn[0]=bn; accn[1]=bn;
  }

  if (t > 0){
    const int tp = dir ? (tt+1) : (tt-1);
    #pragma unroll
    for (int rr = 0; rr < 8; ++rr){
      int row = w*8 + rr;
      const float* srcb = hs + ((size_t)(b0+row)*S + tp)*1024 + dir*512;
      gload16(srcb + l*4,       (char*)hL + (size_t)(row*520)*4);
      gload16(srcb + 256 + l*4, (char*)hL + (size_t)(row*520 + 256)*4);
    }
    for (int c = 0; c < 4; ++c){
      const int k0 = c*128;
      __syncthreads();
      #pragma unroll
      for (int i = 0; i < 6; ++i){
        int qidx = tid + i*256;
        int row = qidx >> 5, q = qidx & 31;
        int grow = (row>>4)*512 + jg*16 + (row & 15);
        f32x4 v = *(const f32x4*)(whh + (size_t)grow*512 + k0 + q*4);
        *(f32x4*)(wL + row*132 + q*4) = v;
      }
      __syncthreads();
      #pragma unroll 4
      for (int q = 0; q < 32; ++q){
        f32x4 ha  = *(const f32x4*)(hL + (2*tb  )*520 + k0 + q*4);
        f32x4 hb  = *(const f32x4*)(hL + (2*tb+1)*520 + k0 + q*4);
        f32x4 wr4 = *(const f32x4*)(wL + tj*132      + q*4);
        f32x4 wz4 = *(const f32x4*)(wL + (16+tj)*132 + q*4);
        f32x4 wn4 = *(const f32x4*)(wL + (32+tj)*132 + q*4);
        #pragma unroll
        for (int e = 0; e < 4; ++e){
          accr[0] += ha[e]*wr4[e]; accz[0] += ha[e]*wz4[e]; accn[0] += ha[e]*wn4[e];
          accr[1] += hb[e]*wr4[e]; accz[1] += hb[e]*wz4[e]; accn[1] += hb[e]*wn4[e];
        }
      }
    }
  }

  #pragma unroll
  for (int bi = 0; bi < 2; ++bi){
    int lb = 2*tb + bi;
    int b = b0 + lb;
    size_t xbase = ((size_t)b*S + tt)*1536;
    float gir = xg[xbase + j], giz = xg[xbase + 512 + j], gin = xg[xbase + 1024 + j];
    float hp = (t>0) ? hL[lb*520 + j] : 0.f;
    float r = sigf(gir + accr[bi]);
    float z = sigf(giz + accz[bi]);
    float n = tanhf(gin + r*accn[bi]);
    hs[((size_t)b*S + tt)*1024 + dir*512 + j] = (1.f - z)*n + z*hp;
  }
}

// sent [b][80][1024] f32 -> sentT [b][1024][96] bf16 (s in [80,96) zero pad)
__global__ void transpose_sent(const float* __restrict__ sent, u16* __restrict__ sentT)
{
  __shared__ float tl[80][65];
  int b = blockIdx.y, h0 = blockIdx.x*64;
  for (int idx = threadIdx.x; idx < 80*64; idx += 256){
    int s = idx >> 6, hh = idx & 63;
    tl[s][hh] = sent[((size_t)b*80 + s)*1024 + h0 + hh];
  }
  __syncthreads();
  for (int idx = threadIdx.x; idx < 64*96; idx += 256){
    int hh = idx / 96, s = idx % 96;
    sentT[((size_t)b*1024 + h0 + hh)*96 + s] = (s < 80) ? f2bf(tl[s][hh]) : (u16)0;
  }
}

__global__ void attn_scores(const float* __restrict__ sent, const float* __restrict__ u,
                            const float* __restrict__ attn_b, float* __restrict__ sc)
{
  int wid = blockIdx.x*4 + (threadIdx.x >> 6);
  int lane = threadIdx.x & 63;
  const float* row = sent + (size_t)wid*1024;
  const float* ub = u + (size_t)(wid/80)*1024;
  float acc = 0.f;
  for (int h = lane; h < 1024; h += 64) acc += row[h]*(ub[h] + attn_b[h]);
  #pragma unroll
  for (int m = 32; m; m >>= 1) acc += __shfl_xor(acc, m);
  if (lane == 0) sc[wid] = acc;
}

// one wave per batch row; 80 values over 64 lanes (lanes 0-15 carry 2)
__global__ void softmax80(const float* __restrict__ sc, float* __restrict__ a)
{
  int b = blockIdx.x, l = threadIdx.x;
  float v0 = sc[b*80 + l];
  float v1 = (l < 16) ? sc[b*80 + 64 + l] : -1e30f;
  float mx = fmaxf(v0, v1);
  #pragma unroll
  for (int m = 32; m; m >>= 1) mx = fmaxf(mx, __shfl_xor(mx, m));
  float e0 = expf(v0 - mx);
  float e1 = (l < 16) ? expf(v1 - mx) : 0.f;
  float s = e0 + e1;
  #pragma unroll
  for (int m = 32; m; m >>= 1) s += __shfl_xor(s, m);
  float inv = 1.f/s;
  a[b*80 + l] = e0*inv;
  if (l < 16) a[b*80 + 64 + l] = e1*inv;
}

__global__ void par_cs0(const float* __restrict__ a, const float* __restrict__ sent,
                        const float* __restrict__ cv, float* __restrict__ Cs0)
{
  int b = blockIdx.x;
  for (int h = threadIdx.x; h < 1024; h += 256){
    float acc = 0.f;
    for (int s = 0; s < 80; ++s) acc += a[b*80+s]*sent[((size_t)b*80+s)*1024 + h];
    Cs0[(size_t)b*2048 + 1024 + h] = acc;
    Cs0[(size_t)b*2048 + h] = cv[(size_t)b*1024 + h];
  }
}

// pack conv weight [O][CIs][3] f32 -> [3][O][CIp] bf16
__global__ void pack_w(const float* __restrict__ src, u16* __restrict__ dst,
                       int O, int CIs, int CIp)
{
  int i = blockIdx.x*256 + threadIdx.x;
  int total = 3*O*CIp;
  if (i >= total) return;
  int tap = i/(O*CIp); int rem = i%(O*CIp); int o = rem/CIp, ci = rem%CIp;
  float v = (ci < CIs) ? src[((size_t)o*CIs + ci)*3 + tap] : 0.f;
  dst[((size_t)tap*O + o)*CIp + ci] = f2bf(v);
}

// pack dense weight [M][Ks] f32 -> [M][Kp] bf16 (zero pad)
__global__ void pack_wk(const float* __restrict__ src, u16* __restrict__ dst,
                        int M, int Ks, int Kp)
{
  int i = blockIdx.x*256 + threadIdx.x;
  if (i >= M*Kp) return;
  int row = i/Kp, k = i%Kp;
  dst[i] = (k < Ks) ? f2bf(src[(size_t)row*Ks + k]) : (u16)0;
}

// elementwise f32 -> bf16
__global__ void pack_f2b(const float* __restrict__ src, u16* __restrict__ dst, int n)
{
  int i = blockIdx.x*256 + threadIdx.x;
  if (i < n) dst[i] = f2bf(src[i]);
}

// gather+pack embeddings: rows R, dst [R][320] bf16
__global__ void pack_x(const float* __restrict__ emb, const int* __restrict__ toks,
                       int rdiv, int rmul, u16* __restrict__ dst, int R)
{
  int i = blockIdx.x*256 + threadIdx.x;
  if (i >= R*320) return;
  int row = i/320, k = i%320;
  int tok = toks[(row/rdiv)*rmul + (row%rdiv)];
  dst[i] = (k < 300) ? f2bf(emb[(size_t)tok*300 + k]) : (u16)0;
}

__global__ void prep_ab(const float* c11b, const float* c13b, const float* c21b, const float* c23b,
                        const float* g1, const float* b1, const float* m1, const float* v1,
                        const float* g2, const float* b2, const float* m2, const float* v2,
                        float* ab)
{
  int i = blockIdx.x*256 + threadIdx.x;
  if (i >= 4096) return;
  int layer = i >> 10, o = i & 1023;
  float al, be;
  if (layer == 0){ al = g1[o]/sqrtf(v1[o]+1e-5f); be = c11b[o]*al + b1[o] - m1[o]*al; }
  else if (layer == 1){ al = 1.f; be = c13b[o]; }
  else if (layer == 2){ al = g2[o]/sqrtf(v2[o]+1e-5f); be = c21b[o]*al + b2[o] - m2[o]*al; }
  else { al = 1.f; be = c23b[o]; }
  ab[layer*2048 + o] = al;
  ab[layer*2048 + 1024 + o] = be;
}

__global__ void init_penc(u32* p){
  int i = blockIdx.x*256 + threadIdx.x;
  if (i < 128*1024) p[i] = encf(-3.3e38f);
}
__global__ void dec_p(const u32* __restrict__ pe, float* __restrict__ pf){
  int i = blockIdx.x*256 + threadIdx.x;
  if (i < 128*1024) pf[i] = decf(pe[i]);
}

// ---------------------------------------------------------------------------
// Conv as 3-tap MFMA GEMM, fine-phase pipeline, v2:
//  - precomputed/strength-reduced addressing (A reads: 1 base + offset:imm,
//    m-independent swizzle since (o>>1)&3 == (lr>>1)&3; B likewise per tap;
//    stage pointers persistent, += 32 u16 per K-step)
//  - ONE barrier per phase (end only) -> waves drift, reads overlap MFMA
//  - counted vmcnt chain (7/7/4) verified: slot staged at phase P is
//    completion-guaranteed >=1 phase before its read, barrier propagates.
// Tile 256o x 256p, 512 thr = 8 waves, wave 128o x 64p.
// LDS 100352 B: 4 x 16KB A slots (depth-3) + 2 x 17408 B B bufs.
// ---------------------------------------------------------------------------
#define CONV_PHASE(TAP, BRD, STAGECODE, WAITCODE)                             \
  {                                                                           \
    const char* Ab = ldsc + (((ks3 + (TAP)) & 3) << 14) + aRd;                \
    const char* Bb = ldsc + 65536 + bpar + (BRD);                             \
    bf16x8 af[8], bfr[4];                                                     \
    _Pragma("unroll")                                                         \
    for (int m=0;m<8;++m) af[m] = *(const bf16x8*)(Ab + m*1024);              \
    _Pragma("unroll")                                                         \
    for (int n=0;n<4;++n) bfr[n] = *(const bf16x8*)(Bb + n*1024);             \
    STAGECODE                                                                 \
    WAITCODE                                                                  \
    __builtin_amdgcn_s_setprio(1);                                            \
    _Pragma("unroll")                                                         \
    for (int n=0;n<4;++n)                                                     \
      _Pragma("unroll")                                                       \
      for (int m=0;m<8;++m)                                                   \
        acc[m][n] = __builtin_amdgcn_mfma_f32_16x16x32_bf16(af[m], bfr[n],    \
                                                            acc[m][n],0,0,0); \
    __builtin_amdgcn_s_setprio(0);                                            \
    asm volatile("" ::: "memory");                                            \
    __builtin_amdgcn_s_barrier();                                             \
    asm volatile("" ::: "memory");                                            \
  }

#define STAGE_A(TAP)                                                          \
      {                                                                       \
        char* Adst = ldsc + (((ks3 + (TAP) + 3) & 3) << 14);                  \
        gload16(aptr0 + (size_t)(TAP)*1024*CI, Adst + aLd0);                  \
        gload16(aptr1 + (size_t)(TAP)*1024*CI, Adst + aLd1);                  \
      }

#define STAGE_B                                                               \
      {                                                                       \
        char* Bdst = ldsc + 65536 + (bpar ^ 17408);                           \
        gload16(bptr0, Bdst + bLd0);                                          \
        gload16(bptr1, Bdst + bLd1);                                          \
        if (l < 8) gload16(bptr2, Bdst + bLd2);                               \
      }

__global__ __launch_bounds__(512,2) void conv_mfma(
    const u16* __restrict__ X, long bstrideX,
    const u16* __restrict__ Wt,
    const float* __restrict__ alpha, const float* __restrict__ beta,
    u16* __restrict__ Y, long bstrideY,
    u32* __restrict__ Penc, int b0,
    int P_in, int P_out, int CI, int dil, int ksteps, int mode)
{
  __shared__ u16 lds[50176];
  char* ldsc = (char*)&lds[0];
  const int tid = threadIdx.x;
  const int l = tid & 63, w = tid >> 6;
  const int wg = blockIdx.x + (blockIdx.y<<2) + (blockIdx.z<<4);
  const int id2 = ((wg & 7) << 5) | (wg >> 3);       // XCD swizzle (bijective)
  const int p0 = (id2 & 3) * 256;
  const int o0 = ((id2 >> 2) & 3) * 256;
  const int bz = id2 >> 4;
  const u16* Xb = X + (size_t)bz * (size_t)bstrideX;
  const int wr = w >> 2, wc = w & 3;
  const int lr = l & 15, g = l >> 4;

  // ---- loop-invariant LDS read bases (swizzle is frag-index independent) ----
  const int aRd  = (wr*128 + lr)*64 + ((g ^ ((lr>>1)&3))<<4);
  const int bRd0 = (wc*64 + lr)*64 + ((g ^ ((lr>>1)&3))<<4);
  const int bRd1 = (wc*64 + lr + dil)*64 + ((g ^ (((lr+dil)>>1)&3))<<4);
  const int bRd2 = (wc*64 + lr + 2*dil)*64 + ((g ^ (((lr+2*dil)>>1)&3))<<4);

  // ---- persistent stage pointers (advance +32 u16 per K-step) ----
  const u16 *aptr0, *aptr1;
  int aLd0, aLd1;
  {
    int c0 = tid,        r0 = c0 >> 2, i0b = (c0 & 3) ^ ((r0>>1)&3);
    int c1 = 512 + tid,  r1 = c1 >> 2, i1b = (c1 & 3) ^ ((r1>>1)&3);
    aptr0 = Wt + ((size_t)(o0 + r0)*CI + i0b*8);  aLd0 = c0*16;
    aptr1 = Wt + ((size_t)(o0 + r1)*CI + i1b*8);  aLd1 = c1*16;
  }
  const u16 *bptr0, *bptr1, *bptr2;
  int bLd0, bLd1, bLd2;
  {
    int c0 = w*136 + l,          r0 = c0 >> 2, i0b = (c0 & 3) ^ ((r0>>1)&3);
    int c1 = w*136 + 64 + l,     r1 = c1 >> 2, i1b = (c1 & 3) ^ ((r1>>1)&3);
    int c2 = w*136 + 128 + (l&7),r2 = c2 >> 2, i2b = (c2 & 3) ^ ((r2>>1)&3);
    int p0c = p0 + r0; p0c = p0c < P_in ? p0c : (P_in-1);
    int p1c = p0 + r1; p1c = p1c < P_in ? p1c : (P_in-1);
    int p2c = p0 + r2; p2c = p2c < P_in ? p2c : (P_in-1);
    bptr0 = Xb + ((size_t)p0c*CI + i0b*8);  bLd0 = c0*16;
    bptr1 = Xb + ((size_t)p1c*CI + i1b*8);  bLd1 = c1*16;
    bptr2 = Xb + ((size_t)p2c*CI + i2b*8);  bLd2 = c2*16;
  }

  f32x4 acc[8][4];
  #pragma unroll
  for (int i=0;i<8;++i)
    #pragma unroll
    for (int j=0;j<4;++j) acc[i][j] = f32x4{0.f,0.f,0.f,0.f};

  // ---- prologue: A slots 0..2 (ks=0 taps) + B buf0; drain once ----
  {
    gload16(aptr0, ldsc + aLd0);
    gload16(aptr1, ldsc + aLd1);
    gload16(aptr0 + (size_t)1024*CI, ldsc + (1<<14) + aLd0);
    gload16(aptr1 + (size_t)1024*CI, ldsc + (1<<14) + aLd1);
    gload16(aptr0 + (size_t)2048*CI, ldsc + (2<<14) + aLd0);
    gload16(aptr1 + (size_t)2048*CI, ldsc + (2<<14) + aLd1);
    gload16(bptr0, ldsc + 65536 + bLd0);
    gload16(bptr1, ldsc + 65536 + bLd1);
    if (l < 8) gload16(bptr2, ldsc + 65536 + bLd2);
    aptr0 += 32; aptr1 += 32; bptr0 += 32; bptr1 += 32; bptr2 += 32;
  }
  asm volatile("s_waitcnt vmcnt(0)" ::: "memory");
  __builtin_amdgcn_s_barrier();
  asm volatile("" ::: "memory");

  int ks3 = 0;
  for (int ks = 0; ks < ksteps-1; ++ks) {
    const int bpar = (ks & 1) ? 17408 : 0;
    CONV_PHASE(0, bRd0,
      STAGE_A(0) STAGE_B,
      asm volatile("s_waitcnt vmcnt(7)" ::: "memory");)
    CONV_PHASE(1, bRd1,
      STAGE_A(1),
      asm volatile("s_waitcnt vmcnt(7)" ::: "memory");)
    CONV_PHASE(2, bRd2,
      STAGE_A(2)
      { aptr0 += 32; aptr1 += 32; bptr0 += 32; bptr1 += 32; bptr2 += 32; },
      asm volatile("s_waitcnt vmcnt(4)" ::: "memory");)
    ks3 += 3;
  }
  {
    const int bpar = ((ksteps-1) & 1) ? 17408 : 0;
    CONV_PHASE(0, bRd0, {},
      asm volatile("s_waitcnt vmcnt(0)" ::: "memory");)
    CONV_PHASE(1, bRd1, {}, {})
    CONV_PHASE(2, bRd2, {}, {})
  }

  if (mode == 2) {
    #pragma unroll
    for (int m=0;m<8;++m){
      int oo = o0 + wr*128 + m*16 + g*4;
      f32x4 al = *(const f32x4*)(alpha + oo);
      f32x4 be = *(const f32x4*)(beta + oo);
      float vm[4] = {-1e30f,-1e30f,-1e30f,-1e30f};
      #pragma unroll
      for (int n=0;n<4;++n){
        int p = p0 + wc*64 + n*16 + lr;
        bool ok = p < P_out;
        #pragma unroll
        for (int r2=0;r2<4;++r2){
          float v = acc[m][n][r2]*al[r2] + be[r2];
          vm[r2] = ok ? fmaxf(vm[r2], v) : vm[r2];
        }
      }
      #pragma unroll
      for (int r2=0;r2<4;++r2){
        float v = vm[r2];
        #pragma unroll
        for (int mask=1; mask<16; mask<<=1) v = fmaxf(v, __shfl_xor(v, mask));
        if (lr == 0) atomicMax(&Penc[(size_t)(b0+bz)*1024 + oo + r2], encf(v));
      }
    }
  } else {
    #pragma unroll
    for (int m=0;m<8;++m){
      int oo = o0 + wr*128 + m*16 + g*4;
      f32x4 al = *(const f32x4*)(alpha + oo);
      f32x4 be = *(const f32x4*)(beta + oo);
      #pragma unroll
      for (int n=0;n<4;++n){
        int p = p0 + wc*64 + n*16 + lr;
        if (p < P_out){
          float v0 = acc[m][n][0]*al[0] + be[0];
          float v1 = acc[m][n][1]*al[1] + be[1];
          float v2 = acc[m][n][2]*al[2] + be[2];
          float v3 = acc[m][n][3]*al[3] + be[3];
          if (mode == 0){ v0=fmaxf(v0,0.f); v1=fmaxf(v1,0.f); v2=fmaxf(v2,0.f); v3=fmaxf(v3,0.f); }
          uint2 pk;
          pk.x = (u32)f2bf(v0) | ((u32)f2bf(v1) << 16);
          pk.y = (u32)f2bf(v2) | ((u32)f2bf(v3) << 16);
          *(uint2*)(Y + (size_t)bz*(size_t)bstrideY + (size_t)p*1024 + oo) = pk;
        }
      }
    }
  }
}

__global__ void head_final(const float* __restrict__ Cs0, const float* __restrict__ t1,
                           const float* __restrict__ t2, const float* __restrict__ outb,
                           float* __restrict__ dout)
{
  __shared__ float red[256];
  int b = blockIdx.x;
  float part = 0.f;
  for (int gg = threadIdx.x; gg < 2048; gg += 256){
    float cd = Cs0[(size_t)b*2048+gg] * sigf(t1[(size_t)b*2048+gg]);
    part += cd * (t2[(size_t)b*2048+gg] + outb[gg]);
  }
  red[threadIdx.x] = part;
  __syncthreads();
  for (int s = 128; s > 0; s >>= 1){
    if (threadIdx.x < s) red[threadIdx.x] += red[threadIdx.x + s];
    __syncthreads();
  }
  if (threadIdx.x < 4) dout[b*4 + threadIdx.x] = red[0];
}

// ---------------------------------------------------------------------------
extern "C" void kernel_launch(void* const* d_in, const int* in_sizes, int n_in,
                              void* d_out, int out_size, void* d_ws, size_t ws_size,
                              hipStream_t stream)
{
  (void)in_sizes; (void)n_in; (void)out_size; (void)ws_size;
  const int*   input_batch = (const int*)d_in[0];
  const int*   choices     = (const int*)d_in[1];
  const float* emb    = (const float*)d_in[2];
  const float* sgwihf = (const float*)d_in[3];
  const float* sgwhhf = (const float*)d_in[4];
  const float* sgbihf = (const float*)d_in[5];
  const float* sgbhhf = (const float*)d_in[6];
  const float* sgwihb = (const float*)d_in[7];
  const float* sgwhhb = (const float*)d_in[8];
  const float* sgbihb = (const float*)d_in[9];
  const float* sgbhhb = (const float*)d_in[10];
  const float* cgwihf = (const float*)d_in[11];
  const float* cgwhhf = (const float*)d_in[12];
  const float* cgbihf = (const float*)d_in[13];
  const float* cgbhhf = (const float*)d_in[14];
  const float* cgwihb = (const float*)d_in[15];
  const float* cgwhhb = (const float*)d_in[16];
  const float* cgbihb = (const float*)d_in[17];
  const float* cgbhhb = (const float*)d_in[18];
  const float* lin_w  = (const float*)d_in[19];
  const float* lin_b  = (const float*)d_in[20];
  const float* attn_w = (const float*)d_in[21];
  const float* attn_b = (const float*)d_in[22];
  const float* c11w = (const float*)d_in[23];
  const float* c11b = (const float*)d_in[24];
  const float* c13w = (const float*)d_in[25];
  const float* c13b = (const float*)d_in[26];
  const float* c21w = (const float*)d_in[27];
  const float* c21b = (const float*)d_in[28];
  const float* c23w = (const float*)d_in[29];
  const float* c23b = (const float*)d_in[30];
  const float* bn1g = (const float*)d_in[31];
  const float* bn1b = (const float*)d_in[32];
  const float* bn1m = (const float*)d_in[33];
  const float* bn1v = (const float*)d_in[34];
  const float* bn2g = (const float*)d_in[35];
  const float* bn2b = (const float*)d_in[36];
  const float* bn2m = (const float*)d_in[37];
  const float* bn2v = (const float*)d_in[38];
  const float* gatewp = (const float*)d_in[39];
  const float* gatewc = (const float*)d_in[40];
  const float* gateb  = (const float*)d_in[41];
  const float* outwp  = (const float*)d_in[42];
  const float* outb   = (const float*)d_in[43];
  float* dout = (float*)d_out;

  char* ws = (char*)d_ws; size_t off = 0;
  auto alc = [&](size_t n)->char*{ char* p = ws + off; off = (off + n + 255) & ~(size_t)255; return p; };
  float* xg_f  = (float*)alc((size_t)128*80*1536*4);   // dead after sentence scan
  float* xg_b  = (float*)alc((size_t)128*80*1536*4);   // (bf16 packs + Y0/Y1 alias here)
  float* xg_cf = (float*)alc((size_t)128*6*1536*4);
  float* xg_cb = (float*)alc((size_t)128*6*1536*4);
  float* gh    = (float*)alc((size_t)2*128*1536*4); (void)gh;
  float* sent  = (float*)alc((size_t)128*80*1024*4);   // dead after par_cs0 (head packs alias)
  float* g_c   = (float*)alc((size_t)128*6*1024*4);
  u16*   sentT = (u16*)alc((size_t)128*1024*96*2);
  float* cv    = (float*)alc((size_t)128*1024*4);
  float* uu    = (float*)alc((size_t)128*1024*4);
  float* scb   = (float*)alc((size_t)128*80*4);
  float* aw    = (float*)alc((size_t)128*80*4);
  float* Cs0   = (float*)alc((size_t)128*2048*4);
  u16* W1p = (u16*)alc((size_t)3*1024*96*2);
  u16* W2p = (u16*)alc((size_t)3*1024*1024*2);
  u16* W3p = (u16*)alc((size_t)3*1024*1024*2);
  u16* W4p = (u16*)alc((size_t)3*1024*1024*2);
  float* ab  = (float*)alc((size_t)4*2048*4);
  u32*  Penc = (u32*)alc((size_t)128*1024*4);
  float* Pf  = (float*)alc((size_t)128*1024*4);
  float* t1  = (float*)alc((size_t)128*2048*4);
  float* t2  = (float*)alc((size_t)128*2048*4);
  u16* xbf_s = (u16*)alc((size_t)10240*320*2);
  u16* xbf_c = (u16*)alc((size_t)768*320*2);
  u16* Wsf = (u16*)alc((size_t)1536*320*2);
  u16* Wsb = (u16*)alc((size_t)1536*320*2);
  u16* Wcf = (u16*)alc((size_t)1536*320*2);
  u16* Wcb = (u16*)alc((size_t)1536*320*2);

  // --- aliased sub-regions (no new high-water allocation) ---
  char* R1 = (char*)xg_f;
  u16* linw_bf  = (u16*)(R1);                      // 12,582,912 B
  u16* attnw_bf = (u16*)(R1 + 12582912);           //  2,097,152 B
  u16* gcbf     = (u16*)(R1 + 14680064);           //  1,572,864 B
  u16* cvbf     = (u16*)(R1 + 16252928);           //    262,144 B
  const int bc = 16;
  u16* Y0 = (u16*)(R1 + 16515072);                 // 33,554,432 B
  u16* Y1 = Y0 + (size_t)bc*1024*1024;             // 33,554,432 B
  char* R2 = (char*)sent;
  u16* gwp_bf = (u16*)(R2);                        // 4,194,304 B
  u16* gwc_bf = (u16*)(R2 + 4194304);              // 8,388,608 B
  u16* owp_bf = (u16*)(R2 + 12582912);             // 4,194,304 B
  u16* Pfbf   = (u16*)(R2 + 16777216);             //   262,144 B
  u16* Cs0bf  = (u16*)(R2 + 17039360);             //   524,288 B

  dim3 T(256), T5(512);

  // ---- prep ----
  pack_w<<<dim3((3*1024*96+255)/256), T, 0, stream>>>(c11w, W1p, 1024, 80, 96);
  pack_w<<<dim3((3*1024*1024+255)/256), T, 0, stream>>>(c13w, W2p, 1024, 1024, 1024);
  pack_w<<<dim3((3*1024*1024+255)/256), T, 0, stream>>>(c21w, W3p, 1024, 1024, 1024);
  pack_w<<<dim3((3*1024*1024+255)/256), T, 0, stream>>>(c23w, W4p, 1024, 1024, 1024);
  pack_wk<<<dim3((1536*320+255)/256), T, 0, stream>>>(sgwihf, Wsf, 1536, 300, 320);
  pack_wk<<<dim3((1536*320+255)/256), T, 0, stream>>>(sgwihb, Wsb, 1536, 300, 320);
  pack_wk<<<dim3((1536*320+255)/256), T, 0, stream>>>(cgwihf, Wcf, 1536, 300, 320);
  pack_wk<<<dim3((1536*320+255)/256), T, 0, stream>>>(cgwihb, Wcb, 1536, 300, 320);
  pack_x<<<dim3((10240*320+255)/256), T, 0, stream>>>(emb, input_batch, 80, 80, xbf_s, 10240);
  pack_x<<<dim3((768*320+255)/256), T, 0, stream>>>(emb, choices, 6, 24, xbf_c, 768);
  prep_ab<<<16, T, 0, stream>>>(c11b, c13b, c21b, c23b,
                                bn1g,bn1b,bn1m,bn1v, bn2g,bn2b,bn2m,bn2v, ab);
  init_penc<<<512, T, 0, stream>>>(Penc);

  // ---- input-gate GEMMs (bf16 MFMA), fwd+bwd via grid.z ----
  gemm_bf16<<<dim3(80,12,2), T, 0, stream>>>(Wsf, Wsb, xbf_s, sgbihf, sgbihb,
                                             xg_f, xg_b, 1536, 320, 10);
  gemm_bf16<<<dim3(6,12,2), T, 0, stream>>>(Wcf, Wcb, xbf_c, cgbihf, cgbihb,
                                            xg_cf, xg_cb, 1536, 320, 10);

  // ---- BiGRU scans ----
  for (int t = 0; t < 80; ++t)
    gru_step<<<dim3(32,4,2), T, 0, stream>>>(xg_f, xg_b, sgwhhf, sgwhhb,
                                             sgbhhf, sgbhhb, sent, 80, t);
  for (int t = 0; t < 6; ++t)
    gru_step<<<dim3(32,4,2), T, 0, stream>>>(xg_cf, xg_cb, cgwhhf, cgwhhb,
                                             cgbhhf, cgbhhb, g_c, 6, t);

  // ---- bf16 packs for lin/attn (xg region now dead) ----
  pack_wk<<<dim3((1024*6144+255)/256), T, 0, stream>>>(lin_w, linw_bf, 1024, 6144, 6144);
  pack_wk<<<dim3((1024*1024+255)/256), T, 0, stream>>>(attn_w, attnw_bf, 1024, 1024, 1024);
  pack_f2b<<<dim3((128*6144+255)/256), T, 0, stream>>>(g_c, gcbf, 128*6144);

  transpose_sent<<<dim3(16,128), T, 0, stream>>>(sent, sentT);

  // ---- choice vector (split-K bf16) + attention ----
  initc<<<dim3((128*1024+255)/256), T, 0, stream>>>(cv, lin_b, 128*1024, 1023);
  gemm_bf16_sk<<<dim3(1,8,6), T, 0, stream>>>(linw_bf, gcbf, cv, 1024, 6144, 32);
  pack_f2b<<<dim3((128*1024+255)/256), T, 0, stream>>>(cv, cvbf, 128*1024);
  initc<<<dim3((128*1024+255)/256), T, 0, stream>>>(uu, nullptr, 128*1024, 1023);
  gemm_bf16_sk<<<dim3(1,8,2), T, 0, stream>>>(attnw_bf, cvbf, uu, 1024, 1024, 16);
  attn_scores<<<2560, T, 0, stream>>>(sent, uu, attn_b, scb);
  softmax80<<<128, dim3(64), 0, stream>>>(scb, aw);
  par_cs0<<<128, T, 0, stream>>>(aw, sent, cv, Cs0);

  // ---- head weight/activation packs (sent region now dead) ----
  pack_wk<<<dim3((2048*1024+255)/256), T, 0, stream>>>(gatewp, gwp_bf, 2048, 1024, 1024);
  pack_wk<<<dim3((2048*2048+255)/256), T, 0, stream>>>(gatewc, gwc_bf, 2048, 2048, 2048);
  pack_wk<<<dim3((2048*1024+255)/256), T, 0, stream>>>(outwp, owp_bf, 2048, 1024, 1024);
  pack_f2b<<<dim3((128*2048+255)/256), T, 0, stream>>>(Cs0, Cs0bf, 128*2048);

  // ---- conv stack (bf16 MFMA, 256x256 tiles, 3-phase pipelined v2) ----
  for (int b0 = 0; b0 < 128; b0 += bc){
    conv_mfma<<<dim3(4,4,bc), T5, 0, stream>>>(sentT + (size_t)b0*1024*96, (long)1024*96,
        W1p, ab+0,    ab+1024, Y0, (long)1024*1024, nullptr, 0, 1024, 1022, 96,   1, 3,  0);
    conv_mfma<<<dim3(4,4,bc), T5, 0, stream>>>(Y0, (long)1024*1024,
        W2p, ab+2048, ab+3072, Y1, (long)1024*1024, nullptr, 0, 1022, 1016, 1024, 3, 32, 1);
    conv_mfma<<<dim3(4,4,bc), T5, 0, stream>>>(Y1, (long)1024*1024,
        W3p, ab+4096, ab+5120, Y0, (long)1024*1024, nullptr, 0, 1016, 1014, 1024, 1, 32, 0);
    conv_mfma<<<dim3(4,4,bc), T5, 0, stream>>>(Y0, (long)1024*1024,
        W4p, ab+6144, ab+7168, nullptr, 0, Penc, b0,          1014, 1008, 1024, 3, 32, 2);
  }
  dec_p<<<512, T, 0, stream>>>(Penc, Pf);
  pack_f2b<<<dim3((128*1024+255)/256), T, 0, stream>>>(Pf, Pfbf, 128*1024);

  // ---- head (split-K bf16) ----
  initc<<<dim3((128*2048+255)/256), T, 0, stream>>>(t1, gateb, 128*2048, 2047);
  gemm_bf16_sk<<<dim3(1,16,2), T, 0, stream>>>(gwp_bf, Pfbf, t1, 2048, 1024, 16);
  gemm_bf16_sk<<<dim3(1,16,4), T, 0, stream>>>(gwc_bf, Cs0bf, t1, 2048, 2048, 16);
  initc<<<dim3((128*2048+255)/256), T, 0, stream>>>(t2, nullptr, 128*2048, 2047);
  gemm_bf16_sk<<<dim3(1,16,2), T, 0, stream>>>(owp_bf, Pfbf, t2, 2048, 1024, 16);
  head_final<<<128, T, 0, stream>>>(Cs0, t1, t2, outb, dout);
}